// Round 7
// baseline (267.449 us; speedup 1.0000x reference)
//
#include <hip/hip_runtime.h>
#include <math.h>

constexpr int CL = 256;
constexpr int CD = 768;
constexpr int CATT = 100;
constexpr int CH = 5;
constexpr int CDK = 20;

__device__ __forceinline__ void fma4(float4& a, float s, const float4& w) {
    a.x = fmaf(s, w.x, a.x);
    a.y = fmaf(s, w.y, a.y);
    a.z = fmaf(s, w.z, a.z);
    a.w = fmaf(s, w.w, a.w);
}

// Async global->LDS, 16B per lane (validated round 6).
__device__ __forceinline__ void gl2lds16(const void* gsrc, void* ldst) {
    __builtin_amdgcn_global_load_lds(
        (const __attribute__((address_space(1))) void*)gsrc,
        (__attribute__((address_space(3))) void*)ldst, 16, 0, 0);
}

// Per-BATCH barrier, fence-minimal (validated round 4: cost ~ join skew).
// RELAXED polls (no per-iteration L2 invalidate), RELEASE arrive, one
// acquire fence on exit. Counter zeroed by the launch memset each replay.
// All 16 blocks of a batch are co-resident (512 blocks = 2/CU guaranteed).
__device__ __forceinline__ void bbar(unsigned* ctr, unsigned target, bool poll) {
    __syncthreads();
    if (threadIdx.x == 0) {
        __hip_atomic_fetch_add(ctr, 1u, __ATOMIC_RELEASE, __HIP_MEMORY_SCOPE_AGENT);
        if (poll) {
            while (__hip_atomic_load(ctr, __ATOMIC_RELAXED, __HIP_MEMORY_SCOPE_AGENT) < target) {
                __builtin_amdgcn_s_sleep(2);
            }
        }
    }
    __syncthreads();
    __builtin_amdgcn_fence(__ATOMIC_ACQUIRE, "agent");
}

// ---------------------------------------------------------------------------
// k1: UNCHANGED from round 6 (verified 65.3 us).
// ---------------------------------------------------------------------------
__global__ __launch_bounds__(256, 3) void k1_fused(
    const float* __restrict__ x, const float* __restrict__ ln_a,
    const float* __restrict__ ln_b, const float* __restrict__ Wxx_w,
    const float* __restrict__ Wxx_b, const float* __restrict__ q_w,
    const float* __restrict__ q_b, const float* __restrict__ k_w,
    const float* __restrict__ k_b, const float* __restrict__ amask,
    float* __restrict__ g, float* __restrict__ qt, float* __restrict__ ktb,
    float* __restrict__ aspect_raw)
{
    __shared__ float s_w[2][3200];
    __shared__ float s_xn[2][16 * 36];
    __shared__ float s_gt[16 * 100];
    __shared__ float s_ln[1536];
    __shared__ float s_mean[16], s_rinv[16];

    const int t = threadIdx.x;
    const int r0 = blockIdx.x * 16;
    const int wid = t >> 6, lane = t & 63;

    if (t < 192) {
        ((float4*)s_ln)[t] = ((const float4*)ln_a)[t];
        ((float4*)(s_ln + 768))[t] = ((const float4*)ln_b)[t];
    }

    for (int rr = wid * 4; rr < wid * 4 + 4; ++rr) {
        const float* xr = x + (size_t)(r0 + rr) * CD;
        float xv[12];
        float s = 0.f;
#pragma unroll
        for (int m = 0; m < 12; ++m) { xv[m] = xr[lane + 64 * m]; s += xv[m]; }
#pragma unroll
        for (int o = 32; o; o >>= 1) s += __shfl_xor(s, o);
        float mean = s * (1.0f / 768.0f);
        float sq = 0.f;
#pragma unroll
        for (int m = 0; m < 12; ++m) { float d = xv[m] - mean; sq = fmaf(d, d, sq); }
#pragma unroll
        for (int o = 32; o; o >>= 1) sq += __shfl_xor(sq, o);
        if (lane == 0) {
            s_mean[rr] = mean;
            s_rinv[rr] = 1.0f / (sqrtf(sq * (1.0f / 767.0f)) + 1e-6f);
        }
    }

    const float4* wsrc = (const float4*)Wxx_w;
    gl2lds16(wsrc + t,       &s_w[0][(t      ) * 4]);
    gl2lds16(wsrc + t + 256, &s_w[0][(t + 256) * 4]);
    gl2lds16(wsrc + t + 512, &s_w[0][(t + 512) * 4]);
    if (t < 32) gl2lds16(wsrc + t + 768, &s_w[0][(t + 768) * 4]);
    const int rA = t >> 5, cA = t & 31;
    float xa = x[(size_t)(r0 + rA) * CD + cA];
    float xb = x[(size_t)(r0 + rA + 8) * CD + cA];

    __syncthreads();

    {
        float la = s_ln[cA], lbv = s_ln[768 + cA];
        s_xn[0][rA * 36 + cA] = fmaf(la, (xa - s_mean[rA]) * s_rinv[rA], lbv);
        s_xn[0][(rA + 8) * 36 + cA] = fmaf(la, (xb - s_mean[rA + 8]) * s_rinv[rA + 8], lbv);
    }
    __syncthreads();

    const int cg = t % 25, rg = t / 25;
    const int c = cg * 4;
    float4 acc0 = make_float4(0.f, 0.f, 0.f, 0.f);
    float4 acc1 = make_float4(0.f, 0.f, 0.f, 0.f);

    for (int kt = 0; kt < 24; ++kt) {
        if (kt < 23) {
            const float4* ws = wsrc + (size_t)(kt + 1) * 800;
            float* wd = s_w[(kt + 1) & 1];
            gl2lds16(ws + t,       wd + (t      ) * 4);
            gl2lds16(ws + t + 256, wd + (t + 256) * 4);
            gl2lds16(ws + t + 512, wd + (t + 512) * 4);
            if (t < 32) gl2lds16(ws + t + 768, wd + (t + 768) * 4);
            int gc = (kt + 1) * 32 + cA;
            xa = x[(size_t)(r0 + rA) * CD + gc];
            xb = x[(size_t)(r0 + rA + 8) * CD + gc];
        }
        if (t < 200) {
            const float* wb = s_w[kt & 1];
            const float* xbuf = s_xn[kt & 1];
#pragma unroll 2
            for (int kk = 0; kk < 32; kk += 4) {
                float4 a0 = *(const float4*)&xbuf[(rg * 2 + 0) * 36 + kk];
                float4 a1 = *(const float4*)&xbuf[(rg * 2 + 1) * 36 + kk];
                float4 v0 = *(const float4*)&wb[(kk + 0) * 100 + c];
                float4 v1 = *(const float4*)&wb[(kk + 1) * 100 + c];
                float4 v2 = *(const float4*)&wb[(kk + 2) * 100 + c];
                float4 v3 = *(const float4*)&wb[(kk + 3) * 100 + c];
                fma4(acc0, a0.x, v0); fma4(acc0, a0.y, v1); fma4(acc0, a0.z, v2); fma4(acc0, a0.w, v3);
                fma4(acc1, a1.x, v0); fma4(acc1, a1.y, v1); fma4(acc1, a1.z, v2); fma4(acc1, a1.w, v3);
            }
        }
        if (kt < 23) {
            int gc = (kt + 1) * 32 + cA;
            float la = s_ln[gc], lbv = s_ln[768 + gc];
            float* xd = s_xn[(kt + 1) & 1];
            xd[rA * 36 + cA] = fmaf(la, (xa - s_mean[rA]) * s_rinv[rA], lbv);
            xd[(rA + 8) * 36 + cA] = fmaf(la, (xb - s_mean[rA + 8]) * s_rinv[rA + 8], lbv);
        }
        __syncthreads();
    }

    if (t < 200) {
        float4 bias = *(const float4*)&Wxx_b[c];
        float4 rv0, rv1;
        rv0.x = acc0.x + bias.x; rv0.y = acc0.y + bias.y; rv0.z = acc0.z + bias.z; rv0.w = acc0.w + bias.w;
        rv1.x = acc1.x + bias.x; rv1.y = acc1.y + bias.y; rv1.z = acc1.z + bias.z; rv1.w = acc1.w + bias.w;
        float4 rv[2] = { rv0, rv1 };
#pragma unroll
        for (int q = 0; q < 2; ++q) {
            int row = r0 + rg * 2 + q;
            *(float4*)&g[(size_t)row * CATT + c] = rv[q];
            *(float4*)&s_gt[(rg * 2 + q) * 100 + c] = rv[q];
            float m = amask[row];
            if (m != 0.f) {
                int b = row >> 8;
                atomicAdd(&aspect_raw[b * CATT + c + 0], m * rv[q].x);
                atomicAdd(&aspect_raw[b * CATT + c + 1], m * rv[q].y);
                atomicAdd(&aspect_raw[b * CATT + c + 2], m * rv[q].z);
                atomicAdd(&aspect_raw[b * CATT + c + 3], m * rv[q].w);
            }
        }
    }

    const float4* qw4 = (const float4*)q_w;
    const float4* kw4 = (const float4*)k_w;
    gl2lds16(qw4 + t, &s_w[0][t * 4]);
    if (t < 244) gl2lds16(qw4 + t + 256, &s_w[0][(t + 256) * 4]);
    __syncthreads();

    float4 p0 = make_float4(0.f, 0.f, 0.f, 0.f);
    float4 p1 = make_float4(0.f, 0.f, 0.f, 0.f);
    for (int tau = 0; tau < 10; ++tau) {
        if (tau < 9) {
            const float4* src = (tau + 1 < 5) ? qw4 + (size_t)(tau + 1) * 500
                                              : kw4 + (size_t)(tau - 4) * 500;
            float* wd = s_w[(tau + 1) & 1];
            gl2lds16(src + t, wd + t * 4);
            if (t < 244) gl2lds16(src + t + 256, wd + (t + 256) * 4);
        }
        if (t < 200) {
            const float* wb = s_w[tau & 1];
            const int kb = (tau % 5) * 20;
#pragma unroll 2
            for (int kk = 0; kk < 20; kk += 4) {
                float4 a0 = *(const float4*)&s_gt[(rg * 2 + 0) * 100 + kb + kk];
                float4 a1 = *(const float4*)&s_gt[(rg * 2 + 1) * 100 + kb + kk];
                float4 v0 = *(const float4*)&wb[(kk + 0) * 100 + c];
                float4 v1 = *(const float4*)&wb[(kk + 1) * 100 + c];
                float4 v2 = *(const float4*)&wb[(kk + 2) * 100 + c];
                float4 v3 = *(const float4*)&wb[(kk + 3) * 100 + c];
                fma4(p0, a0.x, v0); fma4(p0, a0.y, v1); fma4(p0, a0.z, v2); fma4(p0, a0.w, v3);
                fma4(p1, a1.x, v0); fma4(p1, a1.y, v1); fma4(p1, a1.z, v2); fma4(p1, a1.w, v3);
            }
            if (tau == 4 || tau == 9) {
                const float* bb = (tau == 4) ? q_b : k_b;
                float* outp = (tau == 4) ? qt : ktb;
                float4 bias = *(const float4*)&bb[c];
                p0.x += bias.x; p0.y += bias.y; p0.z += bias.z; p0.w += bias.w;
                p1.x += bias.x; p1.y += bias.y; p1.z += bias.z; p1.w += bias.w;
                const int h = c / CDK, d = c % CDK;
                float4 rv[2] = { p0, p1 };
#pragma unroll
                for (int q = 0; q < 2; ++q) {
                    int row = r0 + rg * 2 + q;
                    int bidx = row >> 8, l = row & 255;
                    *(float4*)&outp[((size_t)(bidx * CH + h) * CL + l) * CDK + d] = rv[q];
                }
                p0 = make_float4(0.f, 0.f, 0.f, 0.f);
                p1 = make_float4(0.f, 0.f, 0.f, 0.f);
            }
        }
        __syncthreads();
    }
}

// ---------------------------------------------------------------------------
// k457: fused k45 + k7 + k8 with per-batch barriers.
// Block map (XCD-local batches): xcd=blk&7, slot=blk>>3,
// b=xcd*4+(slot>>4), ic=slot&15.
// Phase A = k45 (attn + GCN0 + rank-1); adjW kept in regs, parked in s_pool
//           LDS across the barrier; gW2S kept in s_gw2 LDS. -> bbar(16)
// Phase B = k7 (GCN1 + pooled atomics), adjW from LDS.      -> bbar(32)
// Phase C = k8 classifier (ic==0 blocks only poll).
// Saves: 2 launch gaps, adjW 16.8MB HBM round-trip, gW2S traffic, k7's
// adjW staging. Barrier machinery validated rounds 4-5.
// ---------------------------------------------------------------------------
__global__ __launch_bounds__(256, 3) void k457_fused(
    const float* __restrict__ qt, const float* __restrict__ ktb,
    const float* __restrict__ aspect_raw, const float* __restrict__ amask,
    const float* __restrict__ dense_w, const float* __restrict__ dense_b,
    const float* __restrict__ bias_m, const int* __restrict__ src_mask,
    const float* __restrict__ shortm, const float* __restrict__ Wx_w,
    const float* __restrict__ g, const float* __restrict__ W_w,
    const float* __restrict__ W_b, const float* __restrict__ Wx_b,
    const float* __restrict__ clf_w, const float* __restrict__ clf_b,
    float* __restrict__ go1, float* __restrict__ t1, float* __restrict__ t2,
    float* __restrict__ out1_raw, unsigned* __restrict__ bar,
    float* __restrict__ out)
{
    constexpr int ICH = 16;
    __shared__ float s_pool[16 * 260];  // adjS | s_ax+s_go | adjW (parked)
    __shared__ float s_w[2][3200];
    __shared__ float s_q[CH * 320];
    __shared__ float s_red[CH][64];
    __shared__ float s_was[5];
    __shared__ float s_aspb[20];
    __shared__ float s_w1[100], s_w2[100];
    __shared__ float s_g1row[16];
    __shared__ float s_gw2[16];

    const int t = threadIdx.x, lane = t & 63, wid = t >> 6;
    const int xcd = blockIdx.x & 7;
    const int slot = blockIdx.x >> 3;
    const int b = xcd * 4 + (slot >> 4);
    const int ic = slot & 15;
    const int i0 = ic * ICH;
    const int j = t;
    unsigned* bctr = bar + b * 32;   // one 128B line per batch

    // =========================== Phase A (k45) ===========================
    float accW[ICH];
    {
        if (t < 5) {
            float s = 0.f;
            for (int k2 = 0; k2 < 5; ++k2) s += Wx_w[t * 5 + k2];
            s_was[t] = s;
        }
        if (t < 100) {
            float a = 0.f, c2 = 0.f;
#pragma unroll
            for (int h = 0; h < 5; ++h) {
                a += Wx_w[(5 + t) * 5 + h];
                c2 += Wx_w[(105 + t) * 5 + h];
            }
            s_w1[t] = a; s_w2[t] = c2;
        }
        float wn = 0.f;
        if (t < 64) {
            float4 mv = ((const float4*)amask)[b * 64 + t];
            wn = mv.x + mv.y + mv.z + mv.w;
#pragma unroll
            for (int o = 32; o; o >>= 1) wn += __shfl_xor(wn, o);
        }
        if (t < 20) {
            float a = 0.f;
            for (int d = 0; d < CATT; ++d)
                a = fmaf(aspect_raw[b * CATT + d], dense_w[d * CDK + t], a);
            s_aspb[t] = a / wn + dense_b[t];
        }
        {
            const float* qbase = qt + (size_t)b * CH * CL * CDK + (size_t)i0 * CDK;
            for (int i = t; i < CH * 320; i += 256) {
                int h = i / 320, r = i % 320;
                s_q[i] = qbase[(size_t)h * CL * CDK + r];
            }
        }

        const bool masked = (src_mask[b * CL + j] == 0);
        const float bm = bias_m[0];
        const float rs20 = 0.223606797749978969f;

        float sm[ICH];
#pragma unroll
        for (int ii = 0; ii < ICH; ++ii)
            sm[ii] = shortm[(size_t)(b * CL + i0 + ii) * CL + j];

        float accS[ICH];
#pragma unroll
        for (int ii = 0; ii < ICH; ++ii) { accS[ii] = 0.f; accW[ii] = 0.f; }

        __syncthreads();

        for (int h = 0; h < CH; ++h) {
            float4 kr[5];
            const float* kp = ktb + ((size_t)(b * CH + h) * CL + j) * CDK;
#pragma unroll
            for (int m = 0; m < 5; ++m) kr[m] = *(const float4*)(kp + 4 * m);
            const float was_h = s_was[h];
            float s = bm;
#pragma unroll
            for (int m = 0; m < 5; ++m) {
                s = fmaf(s_aspb[4 * m + 0], kr[m].x, s);
                s = fmaf(s_aspb[4 * m + 1], kr[m].y, s);
                s = fmaf(s_aspb[4 * m + 2], kr[m].z, s);
                s = fmaf(s_aspb[4 * m + 3], kr[m].w, s);
            }
            const float aspsc = tanhf(s);

            float pv[ICH];
#pragma unroll
            for (int ii = 0; ii < ICH; ++ii) {
                const float* qrow = &s_q[h * 320 + ii * CDK];
                float sc = 0.f;
#pragma unroll
                for (int m = 0; m < 5; ++m) {
                    float4 q4 = *(const float4*)(qrow + 4 * m);
                    sc = fmaf(q4.x, kr[m].x, sc);
                    sc = fmaf(q4.y, kr[m].y, sc);
                    sc = fmaf(q4.z, kr[m].z, sc);
                    sc = fmaf(q4.w, kr[m].w, sc);
                }
                sc = fmaf(sc, rs20, aspsc) + sm[ii];
                float p = masked ? 0.f : __expf(sc);
                pv[ii] = p;
                float ssum = p;
#pragma unroll
                for (int o = 32; o; o >>= 1) ssum += __shfl_xor(ssum, o);
                if (lane == 0) s_red[h][ii * 4 + wid] = ssum;
            }
            __syncthreads();
#pragma unroll
            for (int ii = 0; ii < ICH; ++ii) {
                float tot = s_red[h][ii * 4 + 0] + s_red[h][ii * 4 + 1] +
                            s_red[h][ii * 4 + 2] + s_red[h][ii * 4 + 3];
                float pn = pv[ii] * __frcp_rn(tot);
                accS[ii] += pn;
                accW[ii] = fmaf(was_h, pn, accW[ii]);
            }
        }

#pragma unroll
        for (int ii = 0; ii < ICH; ++ii)
            s_pool[ii * 260 + j] = accS[ii];
    }

    const int cg = t % 25, rg = t / 25;
    const int c = cg * 4;

    {
        // --- GEMM1: Ax = adjS_tile @ g
        const float4* g4 = (const float4*)g + (size_t)b * 6400;
        gl2lds16(g4 + t,       &s_w[0][(t      ) * 4]);
        gl2lds16(g4 + t + 256, &s_w[0][(t + 256) * 4]);
        gl2lds16(g4 + t + 512, &s_w[0][(t + 512) * 4]);
        if (t < 32) gl2lds16(g4 + t + 768, &s_w[0][(t + 768) * 4]);
        __syncthreads();   // s_pool + tile0 visible

        float4 acc0 = make_float4(0.f, 0.f, 0.f, 0.f);
        float4 acc1 = make_float4(0.f, 0.f, 0.f, 0.f);
        for (int jt = 0; jt < 8; ++jt) {
            if (jt < 7) {
                const float4* src = g4 + (size_t)(jt + 1) * 800;
                float* wd = s_w[(jt + 1) & 1];
                gl2lds16(src + t,       wd + (t      ) * 4);
                gl2lds16(src + t + 256, wd + (t + 256) * 4);
                gl2lds16(src + t + 512, wd + (t + 512) * 4);
                if (t < 32) gl2lds16(src + t + 768, wd + (t + 768) * 4);
            }
            if (t < 200) {
                const float* wb = s_w[jt & 1];
#pragma unroll 2
                for (int kk = 0; kk < 32; kk += 4) {
                    float4 a0 = *(const float4*)&s_pool[(rg * 2 + 0) * 260 + jt * 32 + kk];
                    float4 a1 = *(const float4*)&s_pool[(rg * 2 + 1) * 260 + jt * 32 + kk];
                    float4 v0 = *(const float4*)&wb[(kk + 0) * 100 + c];
                    float4 v1 = *(const float4*)&wb[(kk + 1) * 100 + c];
                    float4 v2 = *(const float4*)&wb[(kk + 2) * 100 + c];
                    float4 v3 = *(const float4*)&wb[(kk + 3) * 100 + c];
                    fma4(acc0, a0.x, v0); fma4(acc0, a0.y, v1); fma4(acc0, a0.z, v2); fma4(acc0, a0.w, v3);
                    fma4(acc1, a1.x, v0); fma4(acc1, a1.y, v1); fma4(acc1, a1.z, v2); fma4(acc1, a1.w, v3);
                }
            }
            __syncthreads();
        }

        // s_ax overlay + W_w tile0 async stage
        float* s_ax = s_pool;
        if (t < 200) {
            float4 r;
            r.x = acc0.x * 0.2f; r.y = acc0.y * 0.2f; r.z = acc0.z * 0.2f; r.w = acc0.w * 0.2f;
            *(float4*)&s_ax[(rg * 2 + 0) * 108 + c] = r;
            r.x = acc1.x * 0.2f; r.y = acc1.y * 0.2f; r.z = acc1.z * 0.2f; r.w = acc1.w * 0.2f;
            *(float4*)&s_ax[(rg * 2 + 1) * 108 + c] = r;
        }
        const float4* ww4 = (const float4*)W_w;
        gl2lds16(ww4 + t, &s_w[0][t * 4]);
        if (t < 244) gl2lds16(ww4 + t + 256, &s_w[0][(t + 256) * 4]);
        __syncthreads();

        // --- GEMM2: go1 = relu(Ax @ W_w + W_b)
        float4 o0 = make_float4(0.f, 0.f, 0.f, 0.f);
        float4 o1 = make_float4(0.f, 0.f, 0.f, 0.f);
        for (int wt = 0; wt < 5; ++wt) {
            if (wt < 4) {
                const float4* src = ww4 + (size_t)(wt + 1) * 500;
                float* wd = s_w[(wt + 1) & 1];
                gl2lds16(src + t, wd + t * 4);
                if (t < 244) gl2lds16(src + t + 256, wd + (t + 256) * 4);
            }
            if (t < 200) {
                const float* wb = s_w[wt & 1];
                const int kb = wt * 20;
#pragma unroll 2
                for (int kk = 0; kk < 20; kk += 4) {
                    float4 a0 = *(const float4*)&s_ax[(rg * 2 + 0) * 108 + kb + kk];
                    float4 a1 = *(const float4*)&s_ax[(rg * 2 + 1) * 108 + kb + kk];
                    float4 v0 = *(const float4*)&wb[(kk + 0) * 100 + c];
                    float4 v1 = *(const float4*)&wb[(kk + 1) * 100 + c];
                    float4 v2 = *(const float4*)&wb[(kk + 2) * 100 + c];
                    float4 v3 = *(const float4*)&wb[(kk + 3) * 100 + c];
                    fma4(o0, a0.x, v0); fma4(o0, a0.y, v1); fma4(o0, a0.z, v2); fma4(o0, a0.w, v3);
                    fma4(o1, a1.x, v0); fma4(o1, a1.y, v1); fma4(o1, a1.z, v2); fma4(o1, a1.w, v3);
                }
            }
            __syncthreads();
        }

        float* s_go = s_pool + 1728;
        if (t < 200) {
            float4 bias = *(const float4*)&W_b[c];
            o0.x = fmaxf(o0.x + bias.x, 0.f); o0.y = fmaxf(o0.y + bias.y, 0.f);
            o0.z = fmaxf(o0.z + bias.z, 0.f); o0.w = fmaxf(o0.w + bias.w, 0.f);
            o1.x = fmaxf(o1.x + bias.x, 0.f); o1.y = fmaxf(o1.y + bias.y, 0.f);
            o1.z = fmaxf(o1.z + bias.z, 0.f); o1.w = fmaxf(o1.w + bias.w, 0.f);
            *(float4*)&go1[(size_t)(b * CL + i0 + rg * 2 + 0) * CATT + c] = o0;
            *(float4*)&go1[(size_t)(b * CL + i0 + rg * 2 + 1) * CATT + c] = o1;
            *(float4*)&s_go[(rg * 2 + 0) * 104 + c] = o0;
            *(float4*)&s_go[(rg * 2 + 1) * 104 + c] = o1;
        }
        __syncthreads();

        if (t < 128) {
            int r = t >> 3, seg = t & 7;
            int e0 = seg * 13, e1 = e0 + 13 < 100 ? e0 + 13 : 100;
            float a = 0.f, c2 = 0.f;
            for (int e = e0; e < e1; ++e) {
                float v = s_go[r * 104 + e];
                a = fmaf(v, s_w1[e], a);
                c2 = fmaf(v, s_w2[e], c2);
            }
            a += __shfl_xor(a, 1); a += __shfl_xor(a, 2); a += __shfl_xor(a, 4);
            c2 += __shfl_xor(c2, 1); c2 += __shfl_xor(c2, 2); c2 += __shfl_xor(c2, 4);
            if (seg == 0) {
                s_g1row[r] = a;
                s_gw2[r] = c2;         // block-local: stays in LDS
            }
        }
        __syncthreads();

        if (t < 100) {
            float a = 0.f, s2 = 0.f;
#pragma unroll
            for (int r = 0; r < 16; ++r) {
                float v = s_go[r * 104 + t];
                a = fmaf(s_g1row[r], v, a);
                s2 += v;
            }
            atomicAdd(&t1[b * CATT + t], a);
            atomicAdd(&t2[b * CATT + t], s2);
        }
        __syncthreads();   // s_go readers done before accW overwrites s_pool

        // park adjW tile (block-local) in LDS across the batch barrier
#pragma unroll
        for (int ii = 0; ii < ICH; ++ii)
            s_pool[ii * 260 + j] = accW[ii];
    }

    bbar(bctr, 16, true);   // batch's go1, t1, t2 complete; s_pool holds adjW

    // =========================== Phase B (k7) ============================
    {
        const float4* g4 = (const float4*)go1 + (size_t)b * 6400;
        gl2lds16(g4 + t,       &s_w[0][(t      ) * 4]);
        gl2lds16(g4 + t + 256, &s_w[0][(t + 256) * 4]);
        gl2lds16(g4 + t + 512, &s_w[0][(t + 512) * 4]);
        if (t < 32) gl2lds16(g4 + t + 768, &s_w[0][(t + 768) * 4]);
        __syncthreads();

        float4 acc0 = make_float4(0.f, 0.f, 0.f, 0.f);
        float4 acc1 = make_float4(0.f, 0.f, 0.f, 0.f);
        for (int jt = 0; jt < 8; ++jt) {
            if (jt < 7) {
                const float4* src = g4 + (size_t)(jt + 1) * 800;
                float* wd = s_w[(jt + 1) & 1];
                gl2lds16(src + t,       wd + (t      ) * 4);
                gl2lds16(src + t + 256, wd + (t + 256) * 4);
                gl2lds16(src + t + 512, wd + (t + 512) * 4);
                if (t < 32) gl2lds16(src + t + 768, wd + (t + 768) * 4);
            }
            if (t < 200) {
                const float* wb = s_w[jt & 1];
#pragma unroll 2
                for (int kk = 0; kk < 32; kk += 4) {
                    float4 a0 = *(const float4*)&s_pool[(rg * 2 + 0) * 260 + jt * 32 + kk];
                    float4 a1 = *(const float4*)&s_pool[(rg * 2 + 1) * 260 + jt * 32 + kk];
                    float4 v0 = *(const float4*)&wb[(kk + 0) * 100 + c];
                    float4 v1 = *(const float4*)&wb[(kk + 1) * 100 + c];
                    float4 v2 = *(const float4*)&wb[(kk + 2) * 100 + c];
                    float4 v3 = *(const float4*)&wb[(kk + 3) * 100 + c];
                    fma4(acc0, a0.x, v0); fma4(acc0, a0.y, v1); fma4(acc0, a0.z, v2); fma4(acc0, a0.w, v3);
                    fma4(acc1, a1.x, v0); fma4(acc1, a1.y, v1); fma4(acc1, a1.z, v2); fma4(acc1, a1.w, v3);
                }
            }
            __syncthreads();
        }

        float* s_ax = s_pool;
        if (t < 200) {
            float wxbs = Wx_b[0] + Wx_b[1] + Wx_b[2] + Wx_b[3] + Wx_b[4];
            float4 t1v = *(const float4*)&t1[b * CATT + c];
            float4 t2v = *(const float4*)&t2[b * CATT + c];
            float gw0 = s_gw2[rg * 2 + 0] + wxbs;
            float gw1 = s_gw2[rg * 2 + 1] + wxbs;
            float4 r;
            r.x = (acc0.x + t1v.x + gw0 * t2v.x) * 0.2f;
            r.y = (acc0.y + t1v.y + gw0 * t2v.y) * 0.2f;
            r.z = (acc0.z + t1v.z + gw0 * t2v.z) * 0.2f;
            r.w = (acc0.w + t1v.w + gw0 * t2v.w) * 0.2f;
            *(float4*)&s_ax[(rg * 2 + 0) * 108 + c] = r;
            r.x = (acc1.x + t1v.x + gw1 * t2v.x) * 0.2f;
            r.y = (acc1.y + t1v.y + gw1 * t2v.y) * 0.2f;
            r.z = (acc1.z + t1v.z + gw1 * t2v.z) * 0.2f;
            r.w = (acc1.w + t1v.w + gw1 * t2v.w) * 0.2f;
            *(float4*)&s_ax[(rg * 2 + 1) * 108 + c] = r;
        }
        const float4* ww4 = (const float4*)W_w;
        gl2lds16(ww4 + t, &s_w[0][t * 4]);
        if (t < 244) gl2lds16(ww4 + t + 256, &s_w[0][(t + 256) * 4]);
        __syncthreads();

        float4 o0 = make_float4(0.f, 0.f, 0.f, 0.f);
        float4 o1 = make_float4(0.f, 0.f, 0.f, 0.f);
        for (int wt = 0; wt < 5; ++wt) {
            if (wt < 4) {
                const float4* src = ww4 + (size_t)(wt + 1) * 500;
                float* wd = s_w[(wt + 1) & 1];
                gl2lds16(src + t, wd + t * 4);
                if (t < 244) gl2lds16(src + t + 256, wd + (t + 256) * 4);
            }
            if (t < 200) {
                const float* wb = s_w[wt & 1];
                const int kb = wt * 20;
#pragma unroll 2
                for (int kk = 0; kk < 20; kk += 4) {
                    float4 a0 = *(const float4*)&s_ax[(rg * 2 + 0) * 108 + kb + kk];
                    float4 a1 = *(const float4*)&s_ax[(rg * 2 + 1) * 108 + kb + kk];
                    float4 v0 = *(const float4*)&wb[(kk + 0) * 100 + c];
                    float4 v1 = *(const float4*)&wb[(kk + 1) * 100 + c];
                    float4 v2 = *(const float4*)&wb[(kk + 2) * 100 + c];
                    float4 v3 = *(const float4*)&wb[(kk + 3) * 100 + c];
                    fma4(o0, a0.x, v0); fma4(o0, a0.y, v1); fma4(o0, a0.z, v2); fma4(o0, a0.w, v3);
                    fma4(o1, a1.x, v0); fma4(o1, a1.y, v1); fma4(o1, a1.z, v2); fma4(o1, a1.w, v3);
                }
            }
            __syncthreads();
        }

        if (t < 200) {
            float4 bias = *(const float4*)&W_b[c];
            o0.x = fmaxf(o0.x + bias.x, 0.f); o0.y = fmaxf(o0.y + bias.y, 0.f);
            o0.z = fmaxf(o0.z + bias.z, 0.f); o0.w = fmaxf(o0.w + bias.w, 0.f);
            o1.x = fmaxf(o1.x + bias.x, 0.f); o1.y = fmaxf(o1.y + bias.y, 0.f);
            o1.z = fmaxf(o1.z + bias.z, 0.f); o1.w = fmaxf(o1.w + bias.w, 0.f);
            float4 ov[2] = { o0, o1 };
#pragma unroll
            for (int q = 0; q < 2; ++q) {
                int row = b * CL + i0 + rg * 2 + q;
                float m = amask[row];
                if (m != 0.f) {
                    atomicAdd(&out1_raw[b * CATT + c + 0], m * ov[q].x);
                    atomicAdd(&out1_raw[b * CATT + c + 1], m * ov[q].y);
                    atomicAdd(&out1_raw[b * CATT + c + 2], m * ov[q].z);
                    atomicAdd(&out1_raw[b * CATT + c + 3], m * ov[q].w);
                }
            }
        }
    }

    bbar(bctr, 32, ic == 0);   // batch's out1_raw complete; only ic==0 polls

    // =========================== Phase C (k8) ============================
    if (ic == 0 && t < 64) {
        float4 mv = ((const float4*)amask)[b * 64 + t];
        float wn = mv.x + mv.y + mv.z + mv.w;
#pragma unroll
        for (int o = 32; o; o >>= 1) wn += __shfl_xor(wn, o);
        if (t < 3) {
            float rwn = 1.f / wn;
            float a = clf_b[t];
            for (int d = 0; d < CATT; ++d)
                a = fmaf(out1_raw[b * CATT + d] * rwn, clf_w[d * 3 + t], a);
            out[b * 3 + t] = a;
        }
    }
}

// ---------------------------------------------------------------------------
extern "C" void kernel_launch(void* const* d_in, const int* in_sizes, int n_in,
                              void* d_out, int out_size, void* d_ws, size_t ws_size,
                              hipStream_t stream) {
    const float* seq     = (const float*)d_in[0];
    const int*   srcm    = (const int*)d_in[1];
    const float* amask   = (const float*)d_in[2];
    const float* shortm  = (const float*)d_in[3];
    const float* ln_a    = (const float*)d_in[4];
    const float* ln_b    = (const float*)d_in[5];
    const float* Wxx_w   = (const float*)d_in[6];
    const float* Wxx_b   = (const float*)d_in[7];
    const float* q_w     = (const float*)d_in[8];
    const float* q_b     = (const float*)d_in[9];
    const float* k_w     = (const float*)d_in[10];
    const float* k_b     = (const float*)d_in[11];
    const float* dense_w = (const float*)d_in[12];
    const float* dense_b = (const float*)d_in[13];
    const float* bias_m  = (const float*)d_in[14];
    const float* W_w     = (const float*)d_in[15];
    const float* W_b     = (const float*)d_in[16];
    const float* Wx_w    = (const float*)d_in[17];
    const float* Wx_b    = (const float*)d_in[18];
    const float* clf_w   = (const float*)d_in[19];
    const float* clf_b   = (const float*)d_in[20];
    float* out = (float*)d_out;

    float* ws         = (float*)d_ws;
    float* g          = ws;
    float* qt         = g + 819200;
    float* ktb        = qt + 819200;
    float* go1        = ktb + 819200;
    float* aspect_raw = go1 + 819200;
    float* t1         = aspect_raw + 3200;
    float* t2         = t1 + 3200;
    float* out1_raw   = t2 + 3200;
    unsigned* bar     = (unsigned*)(out1_raw + 3200);   // 32 batches x 32 uints

    // zero accumulators + per-batch barrier counters (graph replay re-zeroes)
    hipMemsetAsync(aspect_raw, 0,
                   4 * 3200 * sizeof(float) + 32 * 32 * sizeof(unsigned), stream);
    hipLaunchKernelGGL(k1_fused, dim3(512), dim3(256), 0, stream, seq, ln_a, ln_b,
                       Wxx_w, Wxx_b, q_w, q_b, k_w, k_b, amask, g, qt, ktb, aspect_raw);
    hipLaunchKernelGGL(k457_fused, dim3(512), dim3(256), 0, stream,
                       qt, ktb, aspect_raw, amask, dense_w, dense_b, bias_m, srcm,
                       shortm, Wx_w, g, W_w, W_b, Wx_b, clf_w, clf_b,
                       go1, t1, t2, out1_raw, bar, out);
}

// Round 9
// 263.668 us; speedup vs baseline: 1.0143x; 1.0143x over previous
//
#include <hip/hip_runtime.h>
#include <math.h>

constexpr int CL = 256;
constexpr int CD = 768;
constexpr int CATT = 100;
constexpr int CH = 5;
constexpr int CDK = 20;

__device__ __forceinline__ void fma4(float4& a, float s, const float4& w) {
    a.x = fmaf(s, w.x, a.x);
    a.y = fmaf(s, w.y, a.y);
    a.z = fmaf(s, w.z, a.z);
    a.w = fmaf(s, w.w, a.w);
}

// Async global->LDS, 16B per lane (validated round 6).
__device__ __forceinline__ void gl2lds16(const void* gsrc, void* ldst) {
    __builtin_amdgcn_global_load_lds(
        (const __attribute__((address_space(1))) void*)gsrc,
        (__attribute__((address_space(3))) void*)ldst, 16, 0, 0);
}

// ---------------------------------------------------------------------------
// k1: LN + g = xn@Wxx + b, q/k GEMMs, masked aspect pooling (atomics).
// GEMM compute is 4x4 register-blocked on 100 threads (was 2x4 on 200):
// per kk-group 8 ds_read_b128 feed 16 fma4 (was 6 per 8) -> 1.5x less LDS
// traffic. k1 is LDS-pipe-bound (r7 analysis: ~3600cy LDS vs ~1000cy VALU
// per tile-pair), so fewer+fatter threads win; idle waves cost nothing.
// ---------------------------------------------------------------------------
__global__ __launch_bounds__(256, 3) void k1_fused(
    const float* __restrict__ x, const float* __restrict__ ln_a,
    const float* __restrict__ ln_b, const float* __restrict__ Wxx_w,
    const float* __restrict__ Wxx_b, const float* __restrict__ q_w,
    const float* __restrict__ q_b, const float* __restrict__ k_w,
    const float* __restrict__ k_b, const float* __restrict__ amask,
    float* __restrict__ g, float* __restrict__ qt, float* __restrict__ ktb,
    float* __restrict__ aspect_raw)
{
    __shared__ float s_w[2][3200];
    __shared__ float s_xn[2][16 * 36];
    __shared__ float s_gt[16 * 100];
    __shared__ float s_ln[1536];
    __shared__ float s_mean[16], s_rinv[16];

    const int t = threadIdx.x;
    const int r0 = blockIdx.x * 16;
    const int wid = t >> 6, lane = t & 63;

    if (t < 192) {
        ((float4*)s_ln)[t] = ((const float4*)ln_a)[t];
        ((float4*)(s_ln + 768))[t] = ((const float4*)ln_b)[t];
    }

    for (int rr = wid * 4; rr < wid * 4 + 4; ++rr) {
        const float* xr = x + (size_t)(r0 + rr) * CD;
        float xv[12];
        float s = 0.f;
#pragma unroll
        for (int m = 0; m < 12; ++m) { xv[m] = xr[lane + 64 * m]; s += xv[m]; }
#pragma unroll
        for (int o = 32; o; o >>= 1) s += __shfl_xor(s, o);
        float mean = s * (1.0f / 768.0f);
        float sq = 0.f;
#pragma unroll
        for (int m = 0; m < 12; ++m) { float d = xv[m] - mean; sq = fmaf(d, d, sq); }
#pragma unroll
        for (int o = 32; o; o >>= 1) sq += __shfl_xor(sq, o);
        if (lane == 0) {
            s_mean[rr] = mean;
            s_rinv[rr] = 1.0f / (sqrtf(sq * (1.0f / 767.0f)) + 1e-6f);
        }
    }

    const float4* wsrc = (const float4*)Wxx_w;
    gl2lds16(wsrc + t,       &s_w[0][(t      ) * 4]);
    gl2lds16(wsrc + t + 256, &s_w[0][(t + 256) * 4]);
    gl2lds16(wsrc + t + 512, &s_w[0][(t + 512) * 4]);
    if (t < 32) gl2lds16(wsrc + t + 768, &s_w[0][(t + 768) * 4]);
    const int rA = t >> 5, cA = t & 31;
    float xa = x[(size_t)(r0 + rA) * CD + cA];
    float xb = x[(size_t)(r0 + rA + 8) * CD + cA];

    __syncthreads();

    {
        float la = s_ln[cA], lbv = s_ln[768 + cA];
        s_xn[0][rA * 36 + cA] = fmaf(la, (xa - s_mean[rA]) * s_rinv[rA], lbv);
        s_xn[0][(rA + 8) * 36 + cA] = fmaf(la, (xb - s_mean[rA + 8]) * s_rinv[rA + 8], lbv);
    }
    __syncthreads();

    const int cg = t % 25, rg = t / 25;   // t<100: rg 0..3 (4 rows each), c 0..96
    const int c = cg * 4;
    float4 acc0 = make_float4(0.f, 0.f, 0.f, 0.f);
    float4 acc1 = make_float4(0.f, 0.f, 0.f, 0.f);
    float4 acc2 = make_float4(0.f, 0.f, 0.f, 0.f);
    float4 acc3 = make_float4(0.f, 0.f, 0.f, 0.f);

    for (int kt = 0; kt < 24; ++kt) {
        if (kt < 23) {
            const float4* ws = wsrc + (size_t)(kt + 1) * 800;
            float* wd = s_w[(kt + 1) & 1];
            gl2lds16(ws + t,       wd + (t      ) * 4);
            gl2lds16(ws + t + 256, wd + (t + 256) * 4);
            gl2lds16(ws + t + 512, wd + (t + 512) * 4);
            if (t < 32) gl2lds16(ws + t + 768, wd + (t + 768) * 4);
            int gc = (kt + 1) * 32 + cA;
            xa = x[(size_t)(r0 + rA) * CD + gc];
            xb = x[(size_t)(r0 + rA + 8) * CD + gc];
        }
        if (t < 100) {
            const float* wb = s_w[kt & 1];
            const float* xbuf = s_xn[kt & 1];
#pragma unroll 2
            for (int kk = 0; kk < 32; kk += 4) {
                float4 a0 = *(const float4*)&xbuf[(rg * 4 + 0) * 36 + kk];
                float4 a1 = *(const float4*)&xbuf[(rg * 4 + 1) * 36 + kk];
                float4 a2 = *(const float4*)&xbuf[(rg * 4 + 2) * 36 + kk];
                float4 a3 = *(const float4*)&xbuf[(rg * 4 + 3) * 36 + kk];
                float4 v0 = *(const float4*)&wb[(kk + 0) * 100 + c];
                float4 v1 = *(const float4*)&wb[(kk + 1) * 100 + c];
                float4 v2 = *(const float4*)&wb[(kk + 2) * 100 + c];
                float4 v3 = *(const float4*)&wb[(kk + 3) * 100 + c];
                fma4(acc0, a0.x, v0); fma4(acc0, a0.y, v1); fma4(acc0, a0.z, v2); fma4(acc0, a0.w, v3);
                fma4(acc1, a1.x, v0); fma4(acc1, a1.y, v1); fma4(acc1, a1.z, v2); fma4(acc1, a1.w, v3);
                fma4(acc2, a2.x, v0); fma4(acc2, a2.y, v1); fma4(acc2, a2.z, v2); fma4(acc2, a2.w, v3);
                fma4(acc3, a3.x, v0); fma4(acc3, a3.y, v1); fma4(acc3, a3.z, v2); fma4(acc3, a3.w, v3);
            }
        }
        if (kt < 23) {
            int gc = (kt + 1) * 32 + cA;
            float la = s_ln[gc], lbv = s_ln[768 + gc];
            float* xd = s_xn[(kt + 1) & 1];
            xd[rA * 36 + cA] = fmaf(la, (xa - s_mean[rA]) * s_rinv[rA], lbv);
            xd[(rA + 8) * 36 + cA] = fmaf(la, (xb - s_mean[rA + 8]) * s_rinv[rA + 8], lbv);
        }
        __syncthreads();
    }

    if (t < 100) {
        float4 bias = *(const float4*)&Wxx_b[c];
        float4 rv[4] = { acc0, acc1, acc2, acc3 };
#pragma unroll
        for (int q = 0; q < 4; ++q) {
            rv[q].x += bias.x; rv[q].y += bias.y; rv[q].z += bias.z; rv[q].w += bias.w;
            int row = r0 + rg * 4 + q;
            *(float4*)&g[(size_t)row * CATT + c] = rv[q];
            *(float4*)&s_gt[(rg * 4 + q) * 100 + c] = rv[q];
            float m = amask[row];
            if (m != 0.f) {
                int b = row >> 8;
                atomicAdd(&aspect_raw[b * CATT + c + 0], m * rv[q].x);
                atomicAdd(&aspect_raw[b * CATT + c + 1], m * rv[q].y);
                atomicAdd(&aspect_raw[b * CATT + c + 2], m * rv[q].z);
                atomicAdd(&aspect_raw[b * CATT + c + 3], m * rv[q].w);
            }
        }
    }

    const float4* qw4 = (const float4*)q_w;
    const float4* kw4 = (const float4*)k_w;
    gl2lds16(qw4 + t, &s_w[0][t * 4]);
    if (t < 244) gl2lds16(qw4 + t + 256, &s_w[0][(t + 256) * 4]);
    __syncthreads();

    float4 p0 = make_float4(0.f, 0.f, 0.f, 0.f);
    float4 p1 = make_float4(0.f, 0.f, 0.f, 0.f);
    float4 p2 = make_float4(0.f, 0.f, 0.f, 0.f);
    float4 p3 = make_float4(0.f, 0.f, 0.f, 0.f);
    for (int tau = 0; tau < 10; ++tau) {
        if (tau < 9) {
            const float4* src = (tau + 1 < 5) ? qw4 + (size_t)(tau + 1) * 500
                                              : kw4 + (size_t)(tau - 4) * 500;
            float* wd = s_w[(tau + 1) & 1];
            gl2lds16(src + t, wd + t * 4);
            if (t < 244) gl2lds16(src + t + 256, wd + (t + 256) * 4);
        }
        if (t < 100) {
            const float* wb = s_w[tau & 1];
            const int kb = (tau % 5) * 20;
#pragma unroll 2
            for (int kk = 0; kk < 20; kk += 4) {
                float4 a0 = *(const float4*)&s_gt[(rg * 4 + 0) * 100 + kb + kk];
                float4 a1 = *(const float4*)&s_gt[(rg * 4 + 1) * 100 + kb + kk];
                float4 a2 = *(const float4*)&s_gt[(rg * 4 + 2) * 100 + kb + kk];
                float4 a3 = *(const float4*)&s_gt[(rg * 4 + 3) * 100 + kb + kk];
                float4 v0 = *(const float4*)&wb[(kk + 0) * 100 + c];
                float4 v1 = *(const float4*)&wb[(kk + 1) * 100 + c];
                float4 v2 = *(const float4*)&wb[(kk + 2) * 100 + c];
                float4 v3 = *(const float4*)&wb[(kk + 3) * 100 + c];
                fma4(p0, a0.x, v0); fma4(p0, a0.y, v1); fma4(p0, a0.z, v2); fma4(p0, a0.w, v3);
                fma4(p1, a1.x, v0); fma4(p1, a1.y, v1); fma4(p1, a1.z, v2); fma4(p1, a1.w, v3);
                fma4(p2, a2.x, v0); fma4(p2, a2.y, v1); fma4(p2, a2.z, v2); fma4(p2, a2.w, v3);
                fma4(p3, a3.x, v0); fma4(p3, a3.y, v1); fma4(p3, a3.z, v2); fma4(p3, a3.w, v3);
            }
            if (tau == 4 || tau == 9) {
                const float* bb = (tau == 4) ? q_b : k_b;
                float* outp = (tau == 4) ? qt : ktb;
                float4 bias = *(const float4*)&bb[c];
                const int h = c / CDK, d = c % CDK;
                float4 rv[4] = { p0, p1, p2, p3 };
#pragma unroll
                for (int q = 0; q < 4; ++q) {
                    rv[q].x += bias.x; rv[q].y += bias.y; rv[q].z += bias.z; rv[q].w += bias.w;
                    int row = r0 + rg * 4 + q;
                    int bidx = row >> 8, l = row & 255;
                    *(float4*)&outp[((size_t)(bidx * CH + h) * CL + l) * CDK + d] = rv[q];
                }
                p0 = make_float4(0.f, 0.f, 0.f, 0.f);
                p1 = make_float4(0.f, 0.f, 0.f, 0.f);
                p2 = make_float4(0.f, 0.f, 0.f, 0.f);
                p3 = make_float4(0.f, 0.f, 0.f, 0.f);
            }
        }
        __syncthreads();
    }
}

// ---------------------------------------------------------------------------
// k45: inline asp + softmax (adjS in LDS, adjW->global) + GCN0 + rank-1.
// GEMM1/GEMM2 compute 4x4-blocked on 100 threads (see k1 header comment).
// ---------------------------------------------------------------------------
__global__ __launch_bounds__(256, 3) void k45_attn_gcn0(
    const float* __restrict__ qt, const float* __restrict__ ktb,
    const float* __restrict__ aspect_raw, const float* __restrict__ amask,
    const float* __restrict__ dense_w, const float* __restrict__ dense_b,
    const float* __restrict__ bias_m, const int* __restrict__ src_mask,
    const float* __restrict__ shortm, const float* __restrict__ Wx_w,
    const float* __restrict__ g, const float* __restrict__ W_w,
    const float* __restrict__ W_b, float* __restrict__ adjW,
    float* __restrict__ go1, float* __restrict__ t1, float* __restrict__ t2,
    float* __restrict__ gW2S)
{
    constexpr int ICH = 16;
    __shared__ float s_pool[16 * 260];
    __shared__ float s_w[2][3200];
    __shared__ float s_q[CH * 320];
    __shared__ float s_red[CH][64];
    __shared__ float s_was[5];
    __shared__ float s_aspb[20];
    __shared__ float s_w1[100], s_w2[100];
    __shared__ float s_g1row[16];

    const int b = blockIdx.x >> 4, ic = blockIdx.x & 15;
    const int i0 = ic * ICH;
    const int t = threadIdx.x, lane = t & 63, wid = t >> 6;
    const int j = t;

    if (t < 5) {
        float s = 0.f;
        for (int k2 = 0; k2 < 5; ++k2) s += Wx_w[t * 5 + k2];
        s_was[t] = s;
    }
    if (t < 100) {
        float a = 0.f, c2 = 0.f;
#pragma unroll
        for (int h = 0; h < 5; ++h) {
            a += Wx_w[(5 + t) * 5 + h];
            c2 += Wx_w[(105 + t) * 5 + h];
        }
        s_w1[t] = a; s_w2[t] = c2;
    }
    float wn = 0.f;
    if (t < 64) {
        float4 mv = ((const float4*)amask)[b * 64 + t];
        wn = mv.x + mv.y + mv.z + mv.w;
#pragma unroll
        for (int o = 32; o; o >>= 1) wn += __shfl_xor(wn, o);
    }
    if (t < 20) {
        float a = 0.f;
        for (int d = 0; d < CATT; ++d)
            a = fmaf(aspect_raw[b * CATT + d], dense_w[d * CDK + t], a);
        s_aspb[t] = a / wn + dense_b[t];
    }
    {
        const float* qbase = qt + (size_t)b * CH * CL * CDK + (size_t)i0 * CDK;
        for (int i = t; i < CH * 320; i += 256) {
            int h = i / 320, r = i % 320;
            s_q[i] = qbase[(size_t)h * CL * CDK + r];
        }
    }

    const bool masked = (src_mask[b * CL + j] == 0);
    const float bm = bias_m[0];
    const float rs20 = 0.223606797749978969f;

    float sm[ICH];
#pragma unroll
    for (int ii = 0; ii < ICH; ++ii)
        sm[ii] = shortm[(size_t)(b * CL + i0 + ii) * CL + j];

    float accS[ICH], accW[ICH];
#pragma unroll
    for (int ii = 0; ii < ICH; ++ii) { accS[ii] = 0.f; accW[ii] = 0.f; }

    __syncthreads();

    for (int h = 0; h < CH; ++h) {
        float4 kr[5];
        const float* kp = ktb + ((size_t)(b * CH + h) * CL + j) * CDK;
#pragma unroll
        for (int m = 0; m < 5; ++m) kr[m] = *(const float4*)(kp + 4 * m);
        const float was_h = s_was[h];
        float s = bm;
#pragma unroll
        for (int m = 0; m < 5; ++m) {
            s = fmaf(s_aspb[4 * m + 0], kr[m].x, s);
            s = fmaf(s_aspb[4 * m + 1], kr[m].y, s);
            s = fmaf(s_aspb[4 * m + 2], kr[m].z, s);
            s = fmaf(s_aspb[4 * m + 3], kr[m].w, s);
        }
        const float aspsc = tanhf(s);

        float pv[ICH];
#pragma unroll
        for (int ii = 0; ii < ICH; ++ii) {
            const float* qrow = &s_q[h * 320 + ii * CDK];
            float sc = 0.f;
#pragma unroll
            for (int m = 0; m < 5; ++m) {
                float4 q4 = *(const float4*)(qrow + 4 * m);
                sc = fmaf(q4.x, kr[m].x, sc);
                sc = fmaf(q4.y, kr[m].y, sc);
                sc = fmaf(q4.z, kr[m].z, sc);
                sc = fmaf(q4.w, kr[m].w, sc);
            }
            sc = fmaf(sc, rs20, aspsc) + sm[ii];
            float p = masked ? 0.f : __expf(sc);
            pv[ii] = p;
            float ssum = p;
#pragma unroll
            for (int o = 32; o; o >>= 1) ssum += __shfl_xor(ssum, o);
            if (lane == 0) s_red[h][ii * 4 + wid] = ssum;
        }
        __syncthreads();
#pragma unroll
        for (int ii = 0; ii < ICH; ++ii) {
            float tot = s_red[h][ii * 4 + 0] + s_red[h][ii * 4 + 1] +
                        s_red[h][ii * 4 + 2] + s_red[h][ii * 4 + 3];
            float pn = pv[ii] * __frcp_rn(tot);
            accS[ii] += pn;
            accW[ii] = fmaf(was_h, pn, accW[ii]);
        }
    }

#pragma unroll
    for (int ii = 0; ii < ICH; ++ii) {
        adjW[(size_t)(b * CL + i0 + ii) * CL + j] = accW[ii];
        s_pool[ii * 260 + j] = accS[ii];
    }

    // --- GEMM1: Ax = adjS_tile @ g (K=256, 8 tiles, gl2lds staged, 4x4)
    const int cg = t % 25, rg = t / 25;
    const int c = cg * 4;
    const float4* g4 = (const float4*)g + (size_t)b * 6400;
    gl2lds16(g4 + t,       &s_w[0][(t      ) * 4]);
    gl2lds16(g4 + t + 256, &s_w[0][(t + 256) * 4]);
    gl2lds16(g4 + t + 512, &s_w[0][(t + 512) * 4]);
    if (t < 32) gl2lds16(g4 + t + 768, &s_w[0][(t + 768) * 4]);
    __syncthreads();

    float4 acc0 = make_float4(0.f, 0.f, 0.f, 0.f);
    float4 acc1 = make_float4(0.f, 0.f, 0.f, 0.f);
    float4 acc2 = make_float4(0.f, 0.f, 0.f, 0.f);
    float4 acc3 = make_float4(0.f, 0.f, 0.f, 0.f);
    for (int jt = 0; jt < 8; ++jt) {
        if (jt < 7) {
            const float4* src = g4 + (size_t)(jt + 1) * 800;
            float* wd = s_w[(jt + 1) & 1];
            gl2lds16(src + t,       wd + (t      ) * 4);
            gl2lds16(src + t + 256, wd + (t + 256) * 4);
            gl2lds16(src + t + 512, wd + (t + 512) * 4);
            if (t < 32) gl2lds16(src + t + 768, wd + (t + 768) * 4);
        }
        if (t < 100) {
            const float* wb = s_w[jt & 1];
#pragma unroll 2
            for (int kk = 0; kk < 32; kk += 4) {
                float4 a0 = *(const float4*)&s_pool[(rg * 4 + 0) * 260 + jt * 32 + kk];
                float4 a1 = *(const float4*)&s_pool[(rg * 4 + 1) * 260 + jt * 32 + kk];
                float4 a2 = *(const float4*)&s_pool[(rg * 4 + 2) * 260 + jt * 32 + kk];
                float4 a3 = *(const float4*)&s_pool[(rg * 4 + 3) * 260 + jt * 32 + kk];
                float4 v0 = *(const float4*)&wb[(kk + 0) * 100 + c];
                float4 v1 = *(const float4*)&wb[(kk + 1) * 100 + c];
                float4 v2 = *(const float4*)&wb[(kk + 2) * 100 + c];
                float4 v3 = *(const float4*)&wb[(kk + 3) * 100 + c];
                fma4(acc0, a0.x, v0); fma4(acc0, a0.y, v1); fma4(acc0, a0.z, v2); fma4(acc0, a0.w, v3);
                fma4(acc1, a1.x, v0); fma4(acc1, a1.y, v1); fma4(acc1, a1.z, v2); fma4(acc1, a1.w, v3);
                fma4(acc2, a2.x, v0); fma4(acc2, a2.y, v1); fma4(acc2, a2.z, v2); fma4(acc2, a2.w, v3);
                fma4(acc3, a3.x, v0); fma4(acc3, a3.y, v1); fma4(acc3, a3.z, v2); fma4(acc3, a3.w, v3);
            }
        }
        __syncthreads();
    }

    // s_ax overlay + W_w tile0 async stage
    float* s_ax = s_pool;
    if (t < 100) {
        float4 av[4] = { acc0, acc1, acc2, acc3 };
#pragma unroll
        for (int q = 0; q < 4; ++q) {
            float4 r;
            r.x = av[q].x * 0.2f; r.y = av[q].y * 0.2f;
            r.z = av[q].z * 0.2f; r.w = av[q].w * 0.2f;
            *(float4*)&s_ax[(rg * 4 + q) * 108 + c] = r;
        }
    }
    const float4* ww4 = (const float4*)W_w;
    gl2lds16(ww4 + t, &s_w[0][t * 4]);
    if (t < 244) gl2lds16(ww4 + t + 256, &s_w[0][(t + 256) * 4]);
    __syncthreads();

    // --- GEMM2: go1 = relu(Ax @ W_w + W_b), 5 tiles, 4x4
    float4 o0 = make_float4(0.f, 0.f, 0.f, 0.f);
    float4 o1 = make_float4(0.f, 0.f, 0.f, 0.f);
    float4 o2 = make_float4(0.f, 0.f, 0.f, 0.f);
    float4 o3 = make_float4(0.f, 0.f, 0.f, 0.f);
    for (int wt = 0; wt < 5; ++wt) {
        if (wt < 4) {
            const float4* src = ww4 + (size_t)(wt + 1) * 500;
            float* wd = s_w[(wt + 1) & 1];
            gl2lds16(src + t, wd + t * 4);
            if (t < 244) gl2lds16(src + t + 256, wd + (t + 256) * 4);
        }
        if (t < 100) {
            const float* wb = s_w[wt & 1];
            const int kb = wt * 20;
#pragma unroll 2
            for (int kk = 0; kk < 20; kk += 4) {
                float4 a0 = *(const float4*)&s_ax[(rg * 4 + 0) * 108 + kb + kk];
                float4 a1 = *(const float4*)&s_ax[(rg * 4 + 1) * 108 + kb + kk];
                float4 a2 = *(const float4*)&s_ax[(rg * 4 + 2) * 108 + kb + kk];
                float4 a3 = *(const float4*)&s_ax[(rg * 4 + 3) * 108 + kb + kk];
                float4 v0 = *(const float4*)&wb[(kk + 0) * 100 + c];
                float4 v1 = *(const float4*)&wb[(kk + 1) * 100 + c];
                float4 v2 = *(const float4*)&wb[(kk + 2) * 100 + c];
                float4 v3 = *(const float4*)&wb[(kk + 3) * 100 + c];
                fma4(o0, a0.x, v0); fma4(o0, a0.y, v1); fma4(o0, a0.z, v2); fma4(o0, a0.w, v3);
                fma4(o1, a1.x, v0); fma4(o1, a1.y, v1); fma4(o1, a1.z, v2); fma4(o1, a1.w, v3);
                fma4(o2, a2.x, v0); fma4(o2, a2.y, v1); fma4(o2, a2.z, v2); fma4(o2, a2.w, v3);
                fma4(o3, a3.x, v0); fma4(o3, a3.y, v1); fma4(o3, a3.z, v2); fma4(o3, a3.w, v3);
            }
        }
        __syncthreads();
    }

    float* s_go = s_pool + 1728;
    if (t < 100) {
        float4 bias = *(const float4*)&W_b[c];
        float4 ov[4] = { o0, o1, o2, o3 };
#pragma unroll
        for (int q = 0; q < 4; ++q) {
            ov[q].x = fmaxf(ov[q].x + bias.x, 0.f);
            ov[q].y = fmaxf(ov[q].y + bias.y, 0.f);
            ov[q].z = fmaxf(ov[q].z + bias.z, 0.f);
            ov[q].w = fmaxf(ov[q].w + bias.w, 0.f);
            *(float4*)&go1[(size_t)(b * CL + i0 + rg * 4 + q) * CATT + c] = ov[q];
            *(float4*)&s_go[(rg * 4 + q) * 104 + c] = ov[q];
        }
    }
    __syncthreads();

    if (t < 128) {
        int r = t >> 3, seg = t & 7;
        int e0 = seg * 13, e1 = e0 + 13 < 100 ? e0 + 13 : 100;
        float a = 0.f, c2 = 0.f;
        for (int e = e0; e < e1; ++e) {
            float v = s_go[r * 104 + e];
            a = fmaf(v, s_w1[e], a);
            c2 = fmaf(v, s_w2[e], c2);
        }
        a += __shfl_xor(a, 1); a += __shfl_xor(a, 2); a += __shfl_xor(a, 4);
        c2 += __shfl_xor(c2, 1); c2 += __shfl_xor(c2, 2); c2 += __shfl_xor(c2, 4);
        if (seg == 0) {
            s_g1row[r] = a;
            gW2S[b * CL + i0 + r] = c2;
        }
    }
    __syncthreads();

    if (t < 100) {
        float a = 0.f, s2 = 0.f;
#pragma unroll
        for (int r = 0; r < 16; ++r) {
            float v = s_go[r * 104 + t];
            a = fmaf(s_g1row[r], v, a);
            s2 += v;
        }
        atomicAdd(&t1[b * CATT + t], a);
        atomicAdd(&t2[b * CATT + t], s2);
    }
}

// ---------------------------------------------------------------------------
// k7: GCN1 with rank-1 corrections; pooled epilogue -> out1_raw atomics.
// GEMMs 4x4-blocked on 100 threads; staging via gl2lds.
// ---------------------------------------------------------------------------
__global__ __launch_bounds__(256, 3) void k7_gcn1(
    const float* __restrict__ adjW, const float* __restrict__ go1,
    const float* __restrict__ W_w, const float* __restrict__ W_b,
    const float* __restrict__ t1, const float* __restrict__ t2,
    const float* __restrict__ gW2S, const float* __restrict__ Wx_b,
    const float* __restrict__ amask, float* __restrict__ out1_raw)
{
    __shared__ float s_pool[16 * 260];
    __shared__ float s_w[2][3200];
    const int b = blockIdx.x >> 4, ic = blockIdx.x & 15;
    const int i0 = ic * 16;
    const int t = threadIdx.x;

    {
        const float4* asrc = (const float4*)adjW + (size_t)(b * CL + i0) * 64;
#pragma unroll
        for (int m = 0; m < 4; ++m) {
            int i = t + 256 * m;
            gl2lds16(asrc + i, &s_pool[(i >> 6) * 260 + (i & 63) * 4]);
        }
    }
    const int cg = t % 25, rg = t / 25;
    const int c = cg * 4;
    const float4* g4 = (const float4*)go1 + (size_t)b * 6400;
    gl2lds16(g4 + t,       &s_w[0][(t      ) * 4]);
    gl2lds16(g4 + t + 256, &s_w[0][(t + 256) * 4]);
    gl2lds16(g4 + t + 512, &s_w[0][(t + 512) * 4]);
    if (t < 32) gl2lds16(g4 + t + 768, &s_w[0][(t + 768) * 4]);
    __syncthreads();

    float4 acc0 = make_float4(0.f, 0.f, 0.f, 0.f);
    float4 acc1 = make_float4(0.f, 0.f, 0.f, 0.f);
    float4 acc2 = make_float4(0.f, 0.f, 0.f, 0.f);
    float4 acc3 = make_float4(0.f, 0.f, 0.f, 0.f);
    for (int jt = 0; jt < 8; ++jt) {
        if (jt < 7) {
            const float4* src = g4 + (size_t)(jt + 1) * 800;
            float* wd = s_w[(jt + 1) & 1];
            gl2lds16(src + t,       wd + (t      ) * 4);
            gl2lds16(src + t + 256, wd + (t + 256) * 4);
            gl2lds16(src + t + 512, wd + (t + 512) * 4);
            if (t < 32) gl2lds16(src + t + 768, wd + (t + 768) * 4);
        }
        if (t < 100) {
            const float* wb = s_w[jt & 1];
#pragma unroll 2
            for (int kk = 0; kk < 32; kk += 4) {
                float4 a0 = *(const float4*)&s_pool[(rg * 4 + 0) * 260 + jt * 32 + kk];
                float4 a1 = *(const float4*)&s_pool[(rg * 4 + 1) * 260 + jt * 32 + kk];
                float4 a2 = *(const float4*)&s_pool[(rg * 4 + 2) * 260 + jt * 32 + kk];
                float4 a3 = *(const float4*)&s_pool[(rg * 4 + 3) * 260 + jt * 32 + kk];
                float4 v0 = *(const float4*)&wb[(kk + 0) * 100 + c];
                float4 v1 = *(const float4*)&wb[(kk + 1) * 100 + c];
                float4 v2 = *(const float4*)&wb[(kk + 2) * 100 + c];
                float4 v3 = *(const float4*)&wb[(kk + 3) * 100 + c];
                fma4(acc0, a0.x, v0); fma4(acc0, a0.y, v1); fma4(acc0, a0.z, v2); fma4(acc0, a0.w, v3);
                fma4(acc1, a1.x, v0); fma4(acc1, a1.y, v1); fma4(acc1, a1.z, v2); fma4(acc1, a1.w, v3);
                fma4(acc2, a2.x, v0); fma4(acc2, a2.y, v1); fma4(acc2, a2.z, v2); fma4(acc2, a2.w, v3);
                fma4(acc3, a3.x, v0); fma4(acc3, a3.y, v1); fma4(acc3, a3.z, v2); fma4(acc3, a3.w, v3);
            }
        }
        __syncthreads();
    }

    float* s_ax = s_pool;
    if (t < 100) {
        float wxbs = Wx_b[0] + Wx_b[1] + Wx_b[2] + Wx_b[3] + Wx_b[4];
        float4 t1v = *(const float4*)&t1[b * CATT + c];
        float4 t2v = *(const float4*)&t2[b * CATT + c];
        float4 av[4] = { acc0, acc1, acc2, acc3 };
#pragma unroll
        for (int q = 0; q < 4; ++q) {
            float gw = gW2S[b * CL + i0 + rg * 4 + q] + wxbs;
            float4 r;
            r.x = (av[q].x + t1v.x + gw * t2v.x) * 0.2f;
            r.y = (av[q].y + t1v.y + gw * t2v.y) * 0.2f;
            r.z = (av[q].z + t1v.z + gw * t2v.z) * 0.2f;
            r.w = (av[q].w + t1v.w + gw * t2v.w) * 0.2f;
            *(float4*)&s_ax[(rg * 4 + q) * 108 + c] = r;
        }
    }
    const float4* ww4 = (const float4*)W_w;
    gl2lds16(ww4 + t, &s_w[0][t * 4]);
    if (t < 244) gl2lds16(ww4 + t + 256, &s_w[0][(t + 256) * 4]);
    __syncthreads();

    float4 o0 = make_float4(0.f, 0.f, 0.f, 0.f);
    float4 o1 = make_float4(0.f, 0.f, 0.f, 0.f);
    float4 o2 = make_float4(0.f, 0.f, 0.f, 0.f);
    float4 o3 = make_float4(0.f, 0.f, 0.f, 0.f);
    for (int wt = 0; wt < 5; ++wt) {
        if (wt < 4) {
            const float4* src = ww4 + (size_t)(wt + 1) * 500;
            float* wd = s_w[(wt + 1) & 1];
            gl2lds16(src + t, wd + t * 4);
            if (t < 244) gl2lds16(src + t + 256, wd + (t + 256) * 4);
        }
        if (t < 100) {
            const float* wb = s_w[wt & 1];
            const int kb = wt * 20;
#pragma unroll 2
            for (int kk = 0; kk < 20; kk += 4) {
                float4 a0 = *(const float4*)&s_ax[(rg * 4 + 0) * 108 + kb + kk];
                float4 a1 = *(const float4*)&s_ax[(rg * 4 + 1) * 108 + kb + kk];
                float4 a2 = *(const float4*)&s_ax[(rg * 4 + 2) * 108 + kb + kk];
                float4 a3 = *(const float4*)&s_ax[(rg * 4 + 3) * 108 + kb + kk];
                float4 v0 = *(const float4*)&wb[(kk + 0) * 100 + c];
                float4 v1 = *(const float4*)&wb[(kk + 1) * 100 + c];
                float4 v2 = *(const float4*)&wb[(kk + 2) * 100 + c];
                float4 v3 = *(const float4*)&wb[(kk + 3) * 100 + c];
                fma4(o0, a0.x, v0); fma4(o0, a0.y, v1); fma4(o0, a0.z, v2); fma4(o0, a0.w, v3);
                fma4(o1, a1.x, v0); fma4(o1, a1.y, v1); fma4(o1, a1.z, v2); fma4(o1, a1.w, v3);
                fma4(o2, a2.x, v0); fma4(o2, a2.y, v1); fma4(o2, a2.z, v2); fma4(o2, a2.w, v3);
                fma4(o3, a3.x, v0); fma4(o3, a3.y, v1); fma4(o3, a3.z, v2); fma4(o3, a3.w, v3);
            }
        }
        __syncthreads();
    }

    if (t < 100) {
        float4 bias = *(const float4*)&W_b[c];
        float4 ov[4] = { o0, o1, o2, o3 };
#pragma unroll
        for (int q = 0; q < 4; ++q) {
            ov[q].x = fmaxf(ov[q].x + bias.x, 0.f);
            ov[q].y = fmaxf(ov[q].y + bias.y, 0.f);
            ov[q].z = fmaxf(ov[q].z + bias.z, 0.f);
            ov[q].w = fmaxf(ov[q].w + bias.w, 0.f);
            int row = b * CL + i0 + rg * 4 + q;
            float m = amask[row];
            if (m != 0.f) {
                atomicAdd(&out1_raw[b * CATT + c + 0], m * ov[q].x);
                atomicAdd(&out1_raw[b * CATT + c + 1], m * ov[q].y);
                atomicAdd(&out1_raw[b * CATT + c + 2], m * ov[q].z);
                atomicAdd(&out1_raw[b * CATT + c + 3], m * ov[q].w);
            }
        }
    }
}

// ---------------------------------------------------------------------------
__global__ __launch_bounds__(64) void k8_small(
    const float* __restrict__ out1_raw, const float* __restrict__ amask,
    const float* __restrict__ clf_w, const float* __restrict__ clf_b,
    float* __restrict__ out)
{
    const int b = blockIdx.x, t = threadIdx.x;
    float4 mv = ((const float4*)amask)[b * 64 + t];
    float wn = mv.x + mv.y + mv.z + mv.w;
#pragma unroll
    for (int o = 32; o; o >>= 1) wn += __shfl_xor(wn, o);
    if (t < 3) {
        float rwn = 1.f / wn;
        float a = clf_b[t];
        for (int d = 0; d < CATT; ++d)
            a = fmaf(out1_raw[b * CATT + d] * rwn, clf_w[d * 3 + t], a);
        out[b * 3 + t] = a;
    }
}

// ---------------------------------------------------------------------------
extern "C" void kernel_launch(void* const* d_in, const int* in_sizes, int n_in,
                              void* d_out, int out_size, void* d_ws, size_t ws_size,
                              hipStream_t stream) {
    const float* seq     = (const float*)d_in[0];
    const int*   srcm    = (const int*)d_in[1];
    const float* amask   = (const float*)d_in[2];
    const float* shortm  = (const float*)d_in[3];
    const float* ln_a    = (const float*)d_in[4];
    const float* ln_b    = (const float*)d_in[5];
    const float* Wxx_w   = (const float*)d_in[6];
    const float* Wxx_b   = (const float*)d_in[7];
    const float* q_w     = (const float*)d_in[8];
    const float* q_b     = (const float*)d_in[9];
    const float* k_w     = (const float*)d_in[10];
    const float* k_b     = (const float*)d_in[11];
    const float* dense_w = (const float*)d_in[12];
    const float* dense_b = (const float*)d_in[13];
    const float* bias_m  = (const float*)d_in[14];
    const float* W_w     = (const float*)d_in[15];
    const float* W_b     = (const float*)d_in[16];
    const float* Wx_w    = (const float*)d_in[17];
    const float* Wx_b    = (const float*)d_in[18];
    const float* clf_w   = (const float*)d_in[19];
    const float* clf_b   = (const float*)d_in[20];
    float* out = (float*)d_out;

    float* ws         = (float*)d_ws;
    float* g          = ws;
    float* qt         = g + 819200;
    float* ktb        = qt + 819200;
    float* go1        = ktb + 819200;
    float* adjW       = go1 + 819200;
    float* aspect_raw = adjW + 2097152;
    float* t1         = aspect_raw + 3200;
    float* t2         = t1 + 3200;
    float* out1_raw   = t2 + 3200;
    float* gW2S       = out1_raw + 3200;

    hipMemsetAsync(aspect_raw, 0, 4 * 3200 * sizeof(float), stream);
    hipLaunchKernelGGL(k1_fused, dim3(512), dim3(256), 0, stream, seq, ln_a, ln_b,
                       Wxx_w, Wxx_b, q_w, q_b, k_w, k_b, amask, g, qt, ktb, aspect_raw);
    hipLaunchKernelGGL(k45_attn_gcn0, dim3(512), dim3(256), 0, stream,
                       qt, ktb, aspect_raw, amask, dense_w, dense_b, bias_m, srcm,
                       shortm, Wx_w, g, W_w, W_b, adjW, go1, t1, t2, gW2S);
    hipLaunchKernelGGL(k7_gcn1, dim3(512), dim3(256), 0, stream,
                       adjW, go1, W_w, W_b, t1, t2, gW2S, Wx_b, amask, out1_raw);
    hipLaunchKernelGGL(k8_small, dim3(32), dim3(64), 0, stream,
                       out1_raw, amask, clf_w, clf_b, out);
}

// Round 10
// 252.158 us; speedup vs baseline: 1.0606x; 1.0456x over previous
//
#include <hip/hip_runtime.h>
#include <math.h>

constexpr int CL = 256;
constexpr int CD = 768;
constexpr int CATT = 100;
constexpr int CH = 5;
constexpr int CDK = 20;

__device__ __forceinline__ void fma4(float4& a, float s, const float4& w) {
    a.x = fmaf(s, w.x, a.x);
    a.y = fmaf(s, w.y, a.y);
    a.z = fmaf(s, w.z, a.z);
    a.w = fmaf(s, w.w, a.w);
}

// Async global->LDS, 16B per lane (validated round 6).
__device__ __forceinline__ void gl2lds16(const void* gsrc, void* ldst) {
    __builtin_amdgcn_global_load_lds(
        (const __attribute__((address_space(1))) void*)gsrc,
        (__attribute__((address_space(3))) void*)ldst, 16, 0, 0);
}

// ---------------------------------------------------------------------------
// k1: round-6 form (verified 65.3 us). 2x4 blocking on 200 threads — round 9
// proved the 4x4/100-thread variant regresses (latency-bound: TLP > per-FLOP
// LDS traffic here). Do not re-narrow the compute thread set.
// ---------------------------------------------------------------------------
__global__ __launch_bounds__(256, 3) void k1_fused(
    const float* __restrict__ x, const float* __restrict__ ln_a,
    const float* __restrict__ ln_b, const float* __restrict__ Wxx_w,
    const float* __restrict__ Wxx_b, const float* __restrict__ q_w,
    const float* __restrict__ q_b, const float* __restrict__ k_w,
    const float* __restrict__ k_b, const float* __restrict__ amask,
    float* __restrict__ g, float* __restrict__ qt, float* __restrict__ ktb,
    float* __restrict__ aspect_raw)
{
    __shared__ float s_w[2][3200];
    __shared__ float s_xn[2][16 * 36];
    __shared__ float s_gt[16 * 100];
    __shared__ float s_ln[1536];
    __shared__ float s_mean[16], s_rinv[16];

    const int t = threadIdx.x;
    const int r0 = blockIdx.x * 16;
    const int wid = t >> 6, lane = t & 63;

    if (t < 192) {
        ((float4*)s_ln)[t] = ((const float4*)ln_a)[t];
        ((float4*)(s_ln + 768))[t] = ((const float4*)ln_b)[t];
    }

    for (int rr = wid * 4; rr < wid * 4 + 4; ++rr) {
        const float* xr = x + (size_t)(r0 + rr) * CD;
        float xv[12];
        float s = 0.f;
#pragma unroll
        for (int m = 0; m < 12; ++m) { xv[m] = xr[lane + 64 * m]; s += xv[m]; }
#pragma unroll
        for (int o = 32; o; o >>= 1) s += __shfl_xor(s, o);
        float mean = s * (1.0f / 768.0f);
        float sq = 0.f;
#pragma unroll
        for (int m = 0; m < 12; ++m) { float d = xv[m] - mean; sq = fmaf(d, d, sq); }
#pragma unroll
        for (int o = 32; o; o >>= 1) sq += __shfl_xor(sq, o);
        if (lane == 0) {
            s_mean[rr] = mean;
            s_rinv[rr] = 1.0f / (sqrtf(sq * (1.0f / 767.0f)) + 1e-6f);
        }
    }

    const float4* wsrc = (const float4*)Wxx_w;
    gl2lds16(wsrc + t,       &s_w[0][(t      ) * 4]);
    gl2lds16(wsrc + t + 256, &s_w[0][(t + 256) * 4]);
    gl2lds16(wsrc + t + 512, &s_w[0][(t + 512) * 4]);
    if (t < 32) gl2lds16(wsrc + t + 768, &s_w[0][(t + 768) * 4]);
    const int rA = t >> 5, cA = t & 31;
    float xa = x[(size_t)(r0 + rA) * CD + cA];
    float xb = x[(size_t)(r0 + rA + 8) * CD + cA];

    __syncthreads();

    {
        float la = s_ln[cA], lbv = s_ln[768 + cA];
        s_xn[0][rA * 36 + cA] = fmaf(la, (xa - s_mean[rA]) * s_rinv[rA], lbv);
        s_xn[0][(rA + 8) * 36 + cA] = fmaf(la, (xb - s_mean[rA + 8]) * s_rinv[rA + 8], lbv);
    }
    __syncthreads();

    const int cg = t % 25, rg = t / 25;
    const int c = cg * 4;
    float4 acc0 = make_float4(0.f, 0.f, 0.f, 0.f);
    float4 acc1 = make_float4(0.f, 0.f, 0.f, 0.f);

    for (int kt = 0; kt < 24; ++kt) {
        if (kt < 23) {
            const float4* ws = wsrc + (size_t)(kt + 1) * 800;
            float* wd = s_w[(kt + 1) & 1];
            gl2lds16(ws + t,       wd + (t      ) * 4);
            gl2lds16(ws + t + 256, wd + (t + 256) * 4);
            gl2lds16(ws + t + 512, wd + (t + 512) * 4);
            if (t < 32) gl2lds16(ws + t + 768, wd + (t + 768) * 4);
            int gc = (kt + 1) * 32 + cA;
            xa = x[(size_t)(r0 + rA) * CD + gc];
            xb = x[(size_t)(r0 + rA + 8) * CD + gc];
        }
        if (t < 200) {
            const float* wb = s_w[kt & 1];
            const float* xbuf = s_xn[kt & 1];
#pragma unroll 2
            for (int kk = 0; kk < 32; kk += 4) {
                float4 a0 = *(const float4*)&xbuf[(rg * 2 + 0) * 36 + kk];
                float4 a1 = *(const float4*)&xbuf[(rg * 2 + 1) * 36 + kk];
                float4 v0 = *(const float4*)&wb[(kk + 0) * 100 + c];
                float4 v1 = *(const float4*)&wb[(kk + 1) * 100 + c];
                float4 v2 = *(const float4*)&wb[(kk + 2) * 100 + c];
                float4 v3 = *(const float4*)&wb[(kk + 3) * 100 + c];
                fma4(acc0, a0.x, v0); fma4(acc0, a0.y, v1); fma4(acc0, a0.z, v2); fma4(acc0, a0.w, v3);
                fma4(acc1, a1.x, v0); fma4(acc1, a1.y, v1); fma4(acc1, a1.z, v2); fma4(acc1, a1.w, v3);
            }
        }
        if (kt < 23) {
            int gc = (kt + 1) * 32 + cA;
            float la = s_ln[gc], lbv = s_ln[768 + gc];
            float* xd = s_xn[(kt + 1) & 1];
            xd[rA * 36 + cA] = fmaf(la, (xa - s_mean[rA]) * s_rinv[rA], lbv);
            xd[(rA + 8) * 36 + cA] = fmaf(la, (xb - s_mean[rA + 8]) * s_rinv[rA + 8], lbv);
        }
        __syncthreads();
    }

    if (t < 200) {
        float4 bias = *(const float4*)&Wxx_b[c];
        float4 rv0, rv1;
        rv0.x = acc0.x + bias.x; rv0.y = acc0.y + bias.y; rv0.z = acc0.z + bias.z; rv0.w = acc0.w + bias.w;
        rv1.x = acc1.x + bias.x; rv1.y = acc1.y + bias.y; rv1.z = acc1.z + bias.z; rv1.w = acc1.w + bias.w;
        float4 rv[2] = { rv0, rv1 };
#pragma unroll
        for (int q = 0; q < 2; ++q) {
            int row = r0 + rg * 2 + q;
            *(float4*)&g[(size_t)row * CATT + c] = rv[q];
            *(float4*)&s_gt[(rg * 2 + q) * 100 + c] = rv[q];
            float m = amask[row];
            if (m != 0.f) {
                int b = row >> 8;
                atomicAdd(&aspect_raw[b * CATT + c + 0], m * rv[q].x);
                atomicAdd(&aspect_raw[b * CATT + c + 1], m * rv[q].y);
                atomicAdd(&aspect_raw[b * CATT + c + 2], m * rv[q].z);
                atomicAdd(&aspect_raw[b * CATT + c + 3], m * rv[q].w);
            }
        }
    }

    const float4* qw4 = (const float4*)q_w;
    const float4* kw4 = (const float4*)k_w;
    gl2lds16(qw4 + t, &s_w[0][t * 4]);
    if (t < 244) gl2lds16(qw4 + t + 256, &s_w[0][(t + 256) * 4]);
    __syncthreads();

    float4 p0 = make_float4(0.f, 0.f, 0.f, 0.f);
    float4 p1 = make_float4(0.f, 0.f, 0.f, 0.f);
    for (int tau = 0; tau < 10; ++tau) {
        if (tau < 9) {
            const float4* src = (tau + 1 < 5) ? qw4 + (size_t)(tau + 1) * 500
                                              : kw4 + (size_t)(tau - 4) * 500;
            float* wd = s_w[(tau + 1) & 1];
            gl2lds16(src + t, wd + t * 4);
            if (t < 244) gl2lds16(src + t + 256, wd + (t + 256) * 4);
        }
        if (t < 200) {
            const float* wb = s_w[tau & 1];
            const int kb = (tau % 5) * 20;
#pragma unroll 2
            for (int kk = 0; kk < 20; kk += 4) {
                float4 a0 = *(const float4*)&s_gt[(rg * 2 + 0) * 100 + kb + kk];
                float4 a1 = *(const float4*)&s_gt[(rg * 2 + 1) * 100 + kb + kk];
                float4 v0 = *(const float4*)&wb[(kk + 0) * 100 + c];
                float4 v1 = *(const float4*)&wb[(kk + 1) * 100 + c];
                float4 v2 = *(const float4*)&wb[(kk + 2) * 100 + c];
                float4 v3 = *(const float4*)&wb[(kk + 3) * 100 + c];
                fma4(p0, a0.x, v0); fma4(p0, a0.y, v1); fma4(p0, a0.z, v2); fma4(p0, a0.w, v3);
                fma4(p1, a1.x, v0); fma4(p1, a1.y, v1); fma4(p1, a1.z, v2); fma4(p1, a1.w, v3);
            }
            if (tau == 4 || tau == 9) {
                const float* bb = (tau == 4) ? q_b : k_b;
                float* outp = (tau == 4) ? qt : ktb;
                float4 bias = *(const float4*)&bb[c];
                p0.x += bias.x; p0.y += bias.y; p0.z += bias.z; p0.w += bias.w;
                p1.x += bias.x; p1.y += bias.y; p1.z += bias.z; p1.w += bias.w;
                const int h = c / CDK, d = c % CDK;
                float4 rv[2] = { p0, p1 };
#pragma unroll
                for (int q = 0; q < 2; ++q) {
                    int row = r0 + rg * 2 + q;
                    int bidx = row >> 8, l = row & 255;
                    *(float4*)&outp[((size_t)(bidx * CH + h) * CL + l) * CDK + d] = rv[q];
                }
                p0 = make_float4(0.f, 0.f, 0.f, 0.f);
                p1 = make_float4(0.f, 0.f, 0.f, 0.f);
            }
        }
        __syncthreads();
    }
}

// ---------------------------------------------------------------------------
// k45: round-6 form + ONE isolated change: next-head kr prefetch in the
// attention h-loop (hides ~300cy L2 latency per head under ~400 VALU ops).
// +~20 VGPR only; no h-loop unroll, no sm[] hoist (round-5's spill causes).
// ---------------------------------------------------------------------------
__global__ __launch_bounds__(256, 3) void k45_attn_gcn0(
    const float* __restrict__ qt, const float* __restrict__ ktb,
    const float* __restrict__ aspect_raw, const float* __restrict__ amask,
    const float* __restrict__ dense_w, const float* __restrict__ dense_b,
    const float* __restrict__ bias_m, const int* __restrict__ src_mask,
    const float* __restrict__ shortm, const float* __restrict__ Wx_w,
    const float* __restrict__ g, const float* __restrict__ W_w,
    const float* __restrict__ W_b, float* __restrict__ adjW,
    float* __restrict__ go1, float* __restrict__ t1, float* __restrict__ t2,
    float* __restrict__ gW2S)
{
    constexpr int ICH = 16;
    __shared__ float s_pool[16 * 260];
    __shared__ float s_w[2][3200];
    __shared__ float s_q[CH * 320];
    __shared__ float s_red[CH][64];
    __shared__ float s_was[5];
    __shared__ float s_aspb[20];
    __shared__ float s_w1[100], s_w2[100];
    __shared__ float s_g1row[16];

    const int b = blockIdx.x >> 4, ic = blockIdx.x & 15;
    const int i0 = ic * ICH;
    const int t = threadIdx.x, lane = t & 63, wid = t >> 6;
    const int j = t;

    if (t < 5) {
        float s = 0.f;
        for (int k2 = 0; k2 < 5; ++k2) s += Wx_w[t * 5 + k2];
        s_was[t] = s;
    }
    if (t < 100) {
        float a = 0.f, c2 = 0.f;
#pragma unroll
        for (int h = 0; h < 5; ++h) {
            a += Wx_w[(5 + t) * 5 + h];
            c2 += Wx_w[(105 + t) * 5 + h];
        }
        s_w1[t] = a; s_w2[t] = c2;
    }
    float wn = 0.f;
    if (t < 64) {
        float4 mv = ((const float4*)amask)[b * 64 + t];
        wn = mv.x + mv.y + mv.z + mv.w;
#pragma unroll
        for (int o = 32; o; o >>= 1) wn += __shfl_xor(wn, o);
    }
    if (t < 20) {
        float a = 0.f;
        for (int d = 0; d < CATT; ++d)
            a = fmaf(aspect_raw[b * CATT + d], dense_w[d * CDK + t], a);
        s_aspb[t] = a / wn + dense_b[t];
    }
    {
        const float* qbase = qt + (size_t)b * CH * CL * CDK + (size_t)i0 * CDK;
        for (int i = t; i < CH * 320; i += 256) {
            int h = i / 320, r = i % 320;
            s_q[i] = qbase[(size_t)h * CL * CDK + r];
        }
    }

    const bool masked = (src_mask[b * CL + j] == 0);
    const float bm = bias_m[0];
    const float rs20 = 0.223606797749978969f;

    float sm[ICH];
#pragma unroll
    for (int ii = 0; ii < ICH; ++ii)
        sm[ii] = shortm[(size_t)(b * CL + i0 + ii) * CL + j];

    float accS[ICH], accW[ICH];
#pragma unroll
    for (int ii = 0; ii < ICH; ++ii) { accS[ii] = 0.f; accW[ii] = 0.f; }

    __syncthreads();

    // next-head kr prefetch: issue head h+1's 5 L2 loads before head h's
    // compute; the swap is register renaming.
    const float* kbase = ktb + (size_t)(b * CH) * CL * CDK + (size_t)j * CDK;
    float4 kr[5];
#pragma unroll
    for (int m = 0; m < 5; ++m) kr[m] = *(const float4*)(kbase + 4 * m);

    for (int h = 0; h < CH; ++h) {
        float4 krn[5];
        if (h < CH - 1) {
            const float* kpn = kbase + (size_t)(h + 1) * CL * CDK;
#pragma unroll
            for (int m = 0; m < 5; ++m) krn[m] = *(const float4*)(kpn + 4 * m);
        }
        const float was_h = s_was[h];
        float s = bm;
#pragma unroll
        for (int m = 0; m < 5; ++m) {
            s = fmaf(s_aspb[4 * m + 0], kr[m].x, s);
            s = fmaf(s_aspb[4 * m + 1], kr[m].y, s);
            s = fmaf(s_aspb[4 * m + 2], kr[m].z, s);
            s = fmaf(s_aspb[4 * m + 3], kr[m].w, s);
        }
        const float aspsc = tanhf(s);

        float pv[ICH];
#pragma unroll
        for (int ii = 0; ii < ICH; ++ii) {
            const float* qrow = &s_q[h * 320 + ii * CDK];
            float sc = 0.f;
#pragma unroll
            for (int m = 0; m < 5; ++m) {
                float4 q4 = *(const float4*)(qrow + 4 * m);
                sc = fmaf(q4.x, kr[m].x, sc);
                sc = fmaf(q4.y, kr[m].y, sc);
                sc = fmaf(q4.z, kr[m].z, sc);
                sc = fmaf(q4.w, kr[m].w, sc);
            }
            sc = fmaf(sc, rs20, aspsc) + sm[ii];
            float p = masked ? 0.f : __expf(sc);
            pv[ii] = p;
            float ssum = p;
#pragma unroll
            for (int o = 32; o; o >>= 1) ssum += __shfl_xor(ssum, o);
            if (lane == 0) s_red[h][ii * 4 + wid] = ssum;
        }
        __syncthreads();
#pragma unroll
        for (int ii = 0; ii < ICH; ++ii) {
            float tot = s_red[h][ii * 4 + 0] + s_red[h][ii * 4 + 1] +
                        s_red[h][ii * 4 + 2] + s_red[h][ii * 4 + 3];
            float pn = pv[ii] * __frcp_rn(tot);
            accS[ii] += pn;
            accW[ii] = fmaf(was_h, pn, accW[ii]);
        }
        if (h < CH - 1) {
#pragma unroll
            for (int m = 0; m < 5; ++m) kr[m] = krn[m];
        }
    }

#pragma unroll
    for (int ii = 0; ii < ICH; ++ii) {
        adjW[(size_t)(b * CL + i0 + ii) * CL + j] = accW[ii];
        s_pool[ii * 260 + j] = accS[ii];
    }

    // --- GEMM1: Ax = adjS_tile @ g (K=256, 8 tiles, global_load_lds staged)
    const int cg = t % 25, rg = t / 25;
    const int c = cg * 4;
    const float4* g4 = (const float4*)g + (size_t)b * 6400;
    gl2lds16(g4 + t,       &s_w[0][(t      ) * 4]);
    gl2lds16(g4 + t + 256, &s_w[0][(t + 256) * 4]);
    gl2lds16(g4 + t + 512, &s_w[0][(t + 512) * 4]);
    if (t < 32) gl2lds16(g4 + t + 768, &s_w[0][(t + 768) * 4]);
    __syncthreads();   // s_pool + tile0 visible

    float4 acc0 = make_float4(0.f, 0.f, 0.f, 0.f);
    float4 acc1 = make_float4(0.f, 0.f, 0.f, 0.f);
    for (int jt = 0; jt < 8; ++jt) {
        if (jt < 7) {
            const float4* src = g4 + (size_t)(jt + 1) * 800;
            float* wd = s_w[(jt + 1) & 1];
            gl2lds16(src + t,       wd + (t      ) * 4);
            gl2lds16(src + t + 256, wd + (t + 256) * 4);
            gl2lds16(src + t + 512, wd + (t + 512) * 4);
            if (t < 32) gl2lds16(src + t + 768, wd + (t + 768) * 4);
        }
        if (t < 200) {
            const float* wb = s_w[jt & 1];
#pragma unroll 2
            for (int kk = 0; kk < 32; kk += 4) {
                float4 a0 = *(const float4*)&s_pool[(rg * 2 + 0) * 260 + jt * 32 + kk];
                float4 a1 = *(const float4*)&s_pool[(rg * 2 + 1) * 260 + jt * 32 + kk];
                float4 v0 = *(const float4*)&wb[(kk + 0) * 100 + c];
                float4 v1 = *(const float4*)&wb[(kk + 1) * 100 + c];
                float4 v2 = *(const float4*)&wb[(kk + 2) * 100 + c];
                float4 v3 = *(const float4*)&wb[(kk + 3) * 100 + c];
                fma4(acc0, a0.x, v0); fma4(acc0, a0.y, v1); fma4(acc0, a0.z, v2); fma4(acc0, a0.w, v3);
                fma4(acc1, a1.x, v0); fma4(acc1, a1.y, v1); fma4(acc1, a1.z, v2); fma4(acc1, a1.w, v3);
            }
        }
        __syncthreads();
    }

    // s_ax overlay + W_w tile0 async stage
    float* s_ax = s_pool;
    if (t < 200) {
        float4 r;
        r.x = acc0.x * 0.2f; r.y = acc0.y * 0.2f; r.z = acc0.z * 0.2f; r.w = acc0.w * 0.2f;
        *(float4*)&s_ax[(rg * 2 + 0) * 108 + c] = r;
        r.x = acc1.x * 0.2f; r.y = acc1.y * 0.2f; r.z = acc1.z * 0.2f; r.w = acc1.w * 0.2f;
        *(float4*)&s_ax[(rg * 2 + 1) * 108 + c] = r;
    }
    const float4* ww4 = (const float4*)W_w;
    gl2lds16(ww4 + t, &s_w[0][t * 4]);
    if (t < 244) gl2lds16(ww4 + t + 256, &s_w[0][(t + 256) * 4]);
    __syncthreads();

    // --- GEMM2: go1 = relu(Ax @ W_w + W_b), 5 tiles
    float4 o0 = make_float4(0.f, 0.f, 0.f, 0.f);
    float4 o1 = make_float4(0.f, 0.f, 0.f, 0.f);
    for (int wt = 0; wt < 5; ++wt) {
        if (wt < 4) {
            const float4* src = ww4 + (size_t)(wt + 1) * 500;
            float* wd = s_w[(wt + 1) & 1];
            gl2lds16(src + t, wd + t * 4);
            if (t < 244) gl2lds16(src + t + 256, wd + (t + 256) * 4);
        }
        if (t < 200) {
            const float* wb = s_w[wt & 1];
            const int kb = wt * 20;
#pragma unroll 2
            for (int kk = 0; kk < 20; kk += 4) {
                float4 a0 = *(const float4*)&s_ax[(rg * 2 + 0) * 108 + kb + kk];
                float4 a1 = *(const float4*)&s_ax[(rg * 2 + 1) * 108 + kb + kk];
                float4 v0 = *(const float4*)&wb[(kk + 0) * 100 + c];
                float4 v1 = *(const float4*)&wb[(kk + 1) * 100 + c];
                float4 v2 = *(const float4*)&wb[(kk + 2) * 100 + c];
                float4 v3 = *(const float4*)&wb[(kk + 3) * 100 + c];
                fma4(o0, a0.x, v0); fma4(o0, a0.y, v1); fma4(o0, a0.z, v2); fma4(o0, a0.w, v3);
                fma4(o1, a1.x, v0); fma4(o1, a1.y, v1); fma4(o1, a1.z, v2); fma4(o1, a1.w, v3);
            }
        }
        __syncthreads();
    }

    float* s_go = s_pool + 1728;
    if (t < 200) {
        float4 bias = *(const float4*)&W_b[c];
        o0.x = fmaxf(o0.x + bias.x, 0.f); o0.y = fmaxf(o0.y + bias.y, 0.f);
        o0.z = fmaxf(o0.z + bias.z, 0.f); o0.w = fmaxf(o0.w + bias.w, 0.f);
        o1.x = fmaxf(o1.x + bias.x, 0.f); o1.y = fmaxf(o1.y + bias.y, 0.f);
        o1.z = fmaxf(o1.z + bias.z, 0.f); o1.w = fmaxf(o1.w + bias.w, 0.f);
        *(float4*)&go1[(size_t)(b * CL + i0 + rg * 2 + 0) * CATT + c] = o0;
        *(float4*)&go1[(size_t)(b * CL + i0 + rg * 2 + 1) * CATT + c] = o1;
        *(float4*)&s_go[(rg * 2 + 0) * 104 + c] = o0;
        *(float4*)&s_go[(rg * 2 + 1) * 104 + c] = o1;
    }
    __syncthreads();

    if (t < 128) {
        int r = t >> 3, seg = t & 7;
        int e0 = seg * 13, e1 = e0 + 13 < 100 ? e0 + 13 : 100;
        float a = 0.f, c2 = 0.f;
        for (int e = e0; e < e1; ++e) {
            float v = s_go[r * 104 + e];
            a = fmaf(v, s_w1[e], a);
            c2 = fmaf(v, s_w2[e], c2);
        }
        a += __shfl_xor(a, 1); a += __shfl_xor(a, 2); a += __shfl_xor(a, 4);
        c2 += __shfl_xor(c2, 1); c2 += __shfl_xor(c2, 2); c2 += __shfl_xor(c2, 4);
        if (seg == 0) {
            s_g1row[r] = a;
            gW2S[b * CL + i0 + r] = c2;
        }
    }
    __syncthreads();

    if (t < 100) {
        float a = 0.f, s2 = 0.f;
#pragma unroll
        for (int r = 0; r < 16; ++r) {
            float v = s_go[r * 104 + t];
            a = fmaf(s_g1row[r], v, a);
            s2 += v;
        }
        atomicAdd(&t1[b * CATT + t], a);
        atomicAdd(&t2[b * CATT + t], s2);
    }
}

// ---------------------------------------------------------------------------
// k7: round-6 form (GCN1 + pooled epilogue; gl2lds staging incl. adjW tile).
// ---------------------------------------------------------------------------
__global__ __launch_bounds__(256, 3) void k7_gcn1(
    const float* __restrict__ adjW, const float* __restrict__ go1,
    const float* __restrict__ W_w, const float* __restrict__ W_b,
    const float* __restrict__ t1, const float* __restrict__ t2,
    const float* __restrict__ gW2S, const float* __restrict__ Wx_b,
    const float* __restrict__ amask, float* __restrict__ out1_raw)
{
    __shared__ float s_pool[16 * 260];
    __shared__ float s_w[2][3200];
    const int b = blockIdx.x >> 4, ic = blockIdx.x & 15;
    const int i0 = ic * 16;
    const int t = threadIdx.x;

    {
        const float4* asrc = (const float4*)adjW + (size_t)(b * CL + i0) * 64;
#pragma unroll
        for (int m = 0; m < 4; ++m) {
            int i = t + 256 * m;
            gl2lds16(asrc + i, &s_pool[(i >> 6) * 260 + (i & 63) * 4]);
        }
    }
    const int cg = t % 25, rg = t / 25;
    const int c = cg * 4;
    const float4* g4 = (const float4*)go1 + (size_t)b * 6400;
    gl2lds16(g4 + t,       &s_w[0][(t      ) * 4]);
    gl2lds16(g4 + t + 256, &s_w[0][(t + 256) * 4]);
    gl2lds16(g4 + t + 512, &s_w[0][(t + 512) * 4]);
    if (t < 32) gl2lds16(g4 + t + 768, &s_w[0][(t + 768) * 4]);
    __syncthreads();

    float4 acc0 = make_float4(0.f, 0.f, 0.f, 0.f);
    float4 acc1 = make_float4(0.f, 0.f, 0.f, 0.f);
    for (int jt = 0; jt < 8; ++jt) {
        if (jt < 7) {
            const float4* src = g4 + (size_t)(jt + 1) * 800;
            float* wd = s_w[(jt + 1) & 1];
            gl2lds16(src + t,       wd + (t      ) * 4);
            gl2lds16(src + t + 256, wd + (t + 256) * 4);
            gl2lds16(src + t + 512, wd + (t + 512) * 4);
            if (t < 32) gl2lds16(src + t + 768, wd + (t + 768) * 4);
        }
        if (t < 200) {
            const float* wb = s_w[jt & 1];
#pragma unroll 2
            for (int kk = 0; kk < 32; kk += 4) {
                float4 a0 = *(const float4*)&s_pool[(rg * 2 + 0) * 260 + jt * 32 + kk];
                float4 a1 = *(const float4*)&s_pool[(rg * 2 + 1) * 260 + jt * 32 + kk];
                float4 v0 = *(const float4*)&wb[(kk + 0) * 100 + c];
                float4 v1 = *(const float4*)&wb[(kk + 1) * 100 + c];
                float4 v2 = *(const float4*)&wb[(kk + 2) * 100 + c];
                float4 v3 = *(const float4*)&wb[(kk + 3) * 100 + c];
                fma4(acc0, a0.x, v0); fma4(acc0, a0.y, v1); fma4(acc0, a0.z, v2); fma4(acc0, a0.w, v3);
                fma4(acc1, a1.x, v0); fma4(acc1, a1.y, v1); fma4(acc1, a1.z, v2); fma4(acc1, a1.w, v3);
            }
        }
        __syncthreads();
    }

    float* s_ax = s_pool;
    if (t < 200) {
        float wxbs = Wx_b[0] + Wx_b[1] + Wx_b[2] + Wx_b[3] + Wx_b[4];
        float4 t1v = *(const float4*)&t1[b * CATT + c];
        float4 t2v = *(const float4*)&t2[b * CATT + c];
        float gw0 = gW2S[b * CL + i0 + rg * 2 + 0] + wxbs;
        float gw1 = gW2S[b * CL + i0 + rg * 2 + 1] + wxbs;
        float4 r;
        r.x = (acc0.x + t1v.x + gw0 * t2v.x) * 0.2f;
        r.y = (acc0.y + t1v.y + gw0 * t2v.y) * 0.2f;
        r.z = (acc0.z + t1v.z + gw0 * t2v.z) * 0.2f;
        r.w = (acc0.w + t1v.w + gw0 * t2v.w) * 0.2f;
        *(float4*)&s_ax[(rg * 2 + 0) * 108 + c] = r;
        r.x = (acc1.x + t1v.x + gw1 * t2v.x) * 0.2f;
        r.y = (acc1.y + t1v.y + gw1 * t2v.y) * 0.2f;
        r.z = (acc1.z + t1v.z + gw1 * t2v.z) * 0.2f;
        r.w = (acc1.w + t1v.w + gw1 * t2v.w) * 0.2f;
        *(float4*)&s_ax[(rg * 2 + 1) * 108 + c] = r;
    }
    const float4* ww4 = (const float4*)W_w;
    gl2lds16(ww4 + t, &s_w[0][t * 4]);
    if (t < 244) gl2lds16(ww4 + t + 256, &s_w[0][(t + 256) * 4]);
    __syncthreads();

    float4 o0 = make_float4(0.f, 0.f, 0.f, 0.f);
    float4 o1 = make_float4(0.f, 0.f, 0.f, 0.f);
    for (int wt = 0; wt < 5; ++wt) {
        if (wt < 4) {
            const float4* src = ww4 + (size_t)(wt + 1) * 500;
            float* wd = s_w[(wt + 1) & 1];
            gl2lds16(src + t, wd + t * 4);
            if (t < 244) gl2lds16(src + t + 256, wd + (t + 256) * 4);
        }
        if (t < 200) {
            const float* wb = s_w[wt & 1];
            const int kb = wt * 20;
#pragma unroll 2
            for (int kk = 0; kk < 20; kk += 4) {
                float4 a0 = *(const float4*)&s_ax[(rg * 2 + 0) * 108 + kb + kk];
                float4 a1 = *(const float4*)&s_ax[(rg * 2 + 1) * 108 + kb + kk];
                float4 v0 = *(const float4*)&wb[(kk + 0) * 100 + c];
                float4 v1 = *(const float4*)&wb[(kk + 1) * 100 + c];
                float4 v2 = *(const float4*)&wb[(kk + 2) * 100 + c];
                float4 v3 = *(const float4*)&wb[(kk + 3) * 100 + c];
                fma4(o0, a0.x, v0); fma4(o0, a0.y, v1); fma4(o0, a0.z, v2); fma4(o0, a0.w, v3);
                fma4(o1, a1.x, v0); fma4(o1, a1.y, v1); fma4(o1, a1.z, v2); fma4(o1, a1.w, v3);
            }
        }
        __syncthreads();
    }

    if (t < 200) {
        float4 bias = *(const float4*)&W_b[c];
        o0.x = fmaxf(o0.x + bias.x, 0.f); o0.y = fmaxf(o0.y + bias.y, 0.f);
        o0.z = fmaxf(o0.z + bias.z, 0.f); o0.w = fmaxf(o0.w + bias.w, 0.f);
        o1.x = fmaxf(o1.x + bias.x, 0.f); o1.y = fmaxf(o1.y + bias.y, 0.f);
        o1.z = fmaxf(o1.z + bias.z, 0.f); o1.w = fmaxf(o1.w + bias.w, 0.f);
        float4 ov[2] = { o0, o1 };
#pragma unroll
        for (int q = 0; q < 2; ++q) {
            int row = b * CL + i0 + rg * 2 + q;
            float m = amask[row];
            if (m != 0.f) {
                atomicAdd(&out1_raw[b * CATT + c + 0], m * ov[q].x);
                atomicAdd(&out1_raw[b * CATT + c + 1], m * ov[q].y);
                atomicAdd(&out1_raw[b * CATT + c + 2], m * ov[q].z);
                atomicAdd(&out1_raw[b * CATT + c + 3], m * ov[q].w);
            }
        }
    }
}

// ---------------------------------------------------------------------------
__global__ __launch_bounds__(64) void k8_small(
    const float* __restrict__ out1_raw, const float* __restrict__ amask,
    const float* __restrict__ clf_w, const float* __restrict__ clf_b,
    float* __restrict__ out)
{
    const int b = blockIdx.x, t = threadIdx.x;
    float4 mv = ((const float4*)amask)[b * 64 + t];
    float wn = mv.x + mv.y + mv.z + mv.w;
#pragma unroll
    for (int o = 32; o; o >>= 1) wn += __shfl_xor(wn, o);
    if (t < 3) {
        float rwn = 1.f / wn;
        float a = clf_b[t];
        for (int d = 0; d < CATT; ++d)
            a = fmaf(out1_raw[b * CATT + d] * rwn, clf_w[d * 3 + t], a);
        out[b * 3 + t] = a;
    }
}

// ---------------------------------------------------------------------------
extern "C" void kernel_launch(void* const* d_in, const int* in_sizes, int n_in,
                              void* d_out, int out_size, void* d_ws, size_t ws_size,
                              hipStream_t stream) {
    const float* seq     = (const float*)d_in[0];
    const int*   srcm    = (const int*)d_in[1];
    const float* amask   = (const float*)d_in[2];
    const float* shortm  = (const float*)d_in[3];
    const float* ln_a    = (const float*)d_in[4];
    const float* ln_b    = (const float*)d_in[5];
    const float* Wxx_w   = (const float*)d_in[6];
    const float* Wxx_b   = (const float*)d_in[7];
    const float* q_w     = (const float*)d_in[8];
    const float* q_b     = (const float*)d_in[9];
    const float* k_w     = (const float*)d_in[10];
    const float* k_b     = (const float*)d_in[11];
    const float* dense_w = (const float*)d_in[12];
    const float* dense_b = (const float*)d_in[13];
    const float* bias_m  = (const float*)d_in[14];
    const float* W_w     = (const float*)d_in[15];
    const float* W_b     = (const float*)d_in[16];
    const float* Wx_w    = (const float*)d_in[17];
    const float* Wx_b    = (const float*)d_in[18];
    const float* clf_w   = (const float*)d_in[19];
    const float* clf_b   = (const float*)d_in[20];
    float* out = (float*)d_out;

    float* ws         = (float*)d_ws;
    float* g          = ws;
    float* qt         = g + 819200;
    float* ktb        = qt + 819200;
    float* go1        = ktb + 819200;
    float* adjW       = go1 + 819200;
    float* aspect_raw = adjW + 2097152;
    float* t1         = aspect_raw + 3200;
    float* t2         = t1 + 3200;
    float* out1_raw   = t2 + 3200;
    float* gW2S       = out1_raw + 3200;

    hipMemsetAsync(aspect_raw, 0, 4 * 3200 * sizeof(float), stream);
    hipLaunchKernelGGL(k1_fused, dim3(512), dim3(256), 0, stream, seq, ln_a, ln_b,
                       Wxx_w, Wxx_b, q_w, q_b, k_w, k_b, amask, g, qt, ktb, aspect_raw);
    hipLaunchKernelGGL(k45_attn_gcn0, dim3(512), dim3(256), 0, stream,
                       qt, ktb, aspect_raw, amask, dense_w, dense_b, bias_m, srcm,
                       shortm, Wx_w, g, W_w, W_b, adjW, go1, t1, t2, gW2S);
    hipLaunchKernelGGL(k7_gcn1, dim3(512), dim3(256), 0, stream,
                       adjW, go1, W_w, W_b, t1, t2, gW2S, Wx_b, amask, out1_raw);
    hipLaunchKernelGGL(k8_small, dim3(32), dim3(64), 0, stream,
                       out1_raw, amask, clf_w, clf_b, out);
}

// Round 11
// 240.590 us; speedup vs baseline: 1.1116x; 1.0481x over previous
//
#include <hip/hip_runtime.h>
#include <math.h>

constexpr int CL = 256;
constexpr int CD = 768;
constexpr int CATT = 100;
constexpr int CH = 5;
constexpr int CDK = 20;

__device__ __forceinline__ void fma4(float4& a, float s, const float4& w) {
    a.x = fmaf(s, w.x, a.x);
    a.y = fmaf(s, w.y, a.y);
    a.z = fmaf(s, w.z, a.z);
    a.w = fmaf(s, w.w, a.w);
}

// Async global->LDS, 16B per lane (validated round 6).
__device__ __forceinline__ void gl2lds16(const void* gsrc, void* ldst) {
    __builtin_amdgcn_global_load_lds(
        (const __attribute__((address_space(1))) void*)gsrc,
        (__attribute__((address_space(3))) void*)ldst, 16, 0, 0);
}

// ---------------------------------------------------------------------------
// k1: LN + g = xn@Wxx + b, q/k GEMMs, masked aspect pooling (atomics).
// Round-6 verified form (65.3 us). 2x4 blocking on 200 threads.
// LESSONS (do not revisit): 4x4/100-thread blocking regresses (r9 — kernel
// is latency-bound, TLP > per-FLOP LDS traffic); full unroll + reg prefetch
// spills (r5); global_load_lds staging is neutral-to-positive (r6).
// ---------------------------------------------------------------------------
__global__ __launch_bounds__(256, 3) void k1_fused(
    const float* __restrict__ x, const float* __restrict__ ln_a,
    const float* __restrict__ ln_b, const float* __restrict__ Wxx_w,
    const float* __restrict__ Wxx_b, const float* __restrict__ q_w,
    const float* __restrict__ q_b, const float* __restrict__ k_w,
    const float* __restrict__ k_b, const float* __restrict__ amask,
    float* __restrict__ g, float* __restrict__ qt, float* __restrict__ ktb,
    float* __restrict__ aspect_raw)
{
    __shared__ float s_w[2][3200];
    __shared__ float s_xn[2][16 * 36];
    __shared__ float s_gt[16 * 100];
    __shared__ float s_ln[1536];
    __shared__ float s_mean[16], s_rinv[16];

    const int t = threadIdx.x;
    const int r0 = blockIdx.x * 16;
    const int wid = t >> 6, lane = t & 63;

    if (t < 192) {
        ((float4*)s_ln)[t] = ((const float4*)ln_a)[t];
        ((float4*)(s_ln + 768))[t] = ((const float4*)ln_b)[t];
    }

    for (int rr = wid * 4; rr < wid * 4 + 4; ++rr) {
        const float* xr = x + (size_t)(r0 + rr) * CD;
        float xv[12];
        float s = 0.f;
#pragma unroll
        for (int m = 0; m < 12; ++m) { xv[m] = xr[lane + 64 * m]; s += xv[m]; }
#pragma unroll
        for (int o = 32; o; o >>= 1) s += __shfl_xor(s, o);
        float mean = s * (1.0f / 768.0f);
        float sq = 0.f;
#pragma unroll
        for (int m = 0; m < 12; ++m) { float d = xv[m] - mean; sq = fmaf(d, d, sq); }
#pragma unroll
        for (int o = 32; o; o >>= 1) sq += __shfl_xor(sq, o);
        if (lane == 0) {
            s_mean[rr] = mean;
            s_rinv[rr] = 1.0f / (sqrtf(sq * (1.0f / 767.0f)) + 1e-6f);
        }
    }

    const float4* wsrc = (const float4*)Wxx_w;
    gl2lds16(wsrc + t,       &s_w[0][(t      ) * 4]);
    gl2lds16(wsrc + t + 256, &s_w[0][(t + 256) * 4]);
    gl2lds16(wsrc + t + 512, &s_w[0][(t + 512) * 4]);
    if (t < 32) gl2lds16(wsrc + t + 768, &s_w[0][(t + 768) * 4]);
    const int rA = t >> 5, cA = t & 31;
    float xa = x[(size_t)(r0 + rA) * CD + cA];
    float xb = x[(size_t)(r0 + rA + 8) * CD + cA];

    __syncthreads();

    {
        float la = s_ln[cA], lbv = s_ln[768 + cA];
        s_xn[0][rA * 36 + cA] = fmaf(la, (xa - s_mean[rA]) * s_rinv[rA], lbv);
        s_xn[0][(rA + 8) * 36 + cA] = fmaf(la, (xb - s_mean[rA + 8]) * s_rinv[rA + 8], lbv);
    }
    __syncthreads();

    const int cg = t % 25, rg = t / 25;
    const int c = cg * 4;
    float4 acc0 = make_float4(0.f, 0.f, 0.f, 0.f);
    float4 acc1 = make_float4(0.f, 0.f, 0.f, 0.f);

    for (int kt = 0; kt < 24; ++kt) {
        if (kt < 23) {
            const float4* ws = wsrc + (size_t)(kt + 1) * 800;
            float* wd = s_w[(kt + 1) & 1];
            gl2lds16(ws + t,       wd + (t      ) * 4);
            gl2lds16(ws + t + 256, wd + (t + 256) * 4);
            gl2lds16(ws + t + 512, wd + (t + 512) * 4);
            if (t < 32) gl2lds16(ws + t + 768, wd + (t + 768) * 4);
            int gc = (kt + 1) * 32 + cA;
            xa = x[(size_t)(r0 + rA) * CD + gc];
            xb = x[(size_t)(r0 + rA + 8) * CD + gc];
        }
        if (t < 200) {
            const float* wb = s_w[kt & 1];
            const float* xbuf = s_xn[kt & 1];
#pragma unroll 2
            for (int kk = 0; kk < 32; kk += 4) {
                float4 a0 = *(const float4*)&xbuf[(rg * 2 + 0) * 36 + kk];
                float4 a1 = *(const float4*)&xbuf[(rg * 2 + 1) * 36 + kk];
                float4 v0 = *(const float4*)&wb[(kk + 0) * 100 + c];
                float4 v1 = *(const float4*)&wb[(kk + 1) * 100 + c];
                float4 v2 = *(const float4*)&wb[(kk + 2) * 100 + c];
                float4 v3 = *(const float4*)&wb[(kk + 3) * 100 + c];
                fma4(acc0, a0.x, v0); fma4(acc0, a0.y, v1); fma4(acc0, a0.z, v2); fma4(acc0, a0.w, v3);
                fma4(acc1, a1.x, v0); fma4(acc1, a1.y, v1); fma4(acc1, a1.z, v2); fma4(acc1, a1.w, v3);
            }
        }
        if (kt < 23) {
            int gc = (kt + 1) * 32 + cA;
            float la = s_ln[gc], lbv = s_ln[768 + gc];
            float* xd = s_xn[(kt + 1) & 1];
            xd[rA * 36 + cA] = fmaf(la, (xa - s_mean[rA]) * s_rinv[rA], lbv);
            xd[(rA + 8) * 36 + cA] = fmaf(la, (xb - s_mean[rA + 8]) * s_rinv[rA + 8], lbv);
        }
        __syncthreads();
    }

    if (t < 200) {
        float4 bias = *(const float4*)&Wxx_b[c];
        float4 rv0, rv1;
        rv0.x = acc0.x + bias.x; rv0.y = acc0.y + bias.y; rv0.z = acc0.z + bias.z; rv0.w = acc0.w + bias.w;
        rv1.x = acc1.x + bias.x; rv1.y = acc1.y + bias.y; rv1.z = acc1.z + bias.z; rv1.w = acc1.w + bias.w;
        float4 rv[2] = { rv0, rv1 };
#pragma unroll
        for (int q = 0; q < 2; ++q) {
            int row = r0 + rg * 2 + q;
            *(float4*)&g[(size_t)row * CATT + c] = rv[q];
            *(float4*)&s_gt[(rg * 2 + q) * 100 + c] = rv[q];
            float m = amask[row];
            if (m != 0.f) {
                int b = row >> 8;
                atomicAdd(&aspect_raw[b * CATT + c + 0], m * rv[q].x);
                atomicAdd(&aspect_raw[b * CATT + c + 1], m * rv[q].y);
                atomicAdd(&aspect_raw[b * CATT + c + 2], m * rv[q].z);
                atomicAdd(&aspect_raw[b * CATT + c + 3], m * rv[q].w);
            }
        }
    }

    const float4* qw4 = (const float4*)q_w;
    const float4* kw4 = (const float4*)k_w;
    gl2lds16(qw4 + t, &s_w[0][t * 4]);
    if (t < 244) gl2lds16(qw4 + t + 256, &s_w[0][(t + 256) * 4]);
    __syncthreads();

    float4 p0 = make_float4(0.f, 0.f, 0.f, 0.f);
    float4 p1 = make_float4(0.f, 0.f, 0.f, 0.f);
    for (int tau = 0; tau < 10; ++tau) {
        if (tau < 9) {
            const float4* src = (tau + 1 < 5) ? qw4 + (size_t)(tau + 1) * 500
                                              : kw4 + (size_t)(tau - 4) * 500;
            float* wd = s_w[(tau + 1) & 1];
            gl2lds16(src + t, wd + t * 4);
            if (t < 244) gl2lds16(src + t + 256, wd + (t + 256) * 4);
        }
        if (t < 200) {
            const float* wb = s_w[tau & 1];
            const int kb = (tau % 5) * 20;
#pragma unroll 2
            for (int kk = 0; kk < 20; kk += 4) {
                float4 a0 = *(const float4*)&s_gt[(rg * 2 + 0) * 100 + kb + kk];
                float4 a1 = *(const float4*)&s_gt[(rg * 2 + 1) * 100 + kb + kk];
                float4 v0 = *(const float4*)&wb[(kk + 0) * 100 + c];
                float4 v1 = *(const float4*)&wb[(kk + 1) * 100 + c];
                float4 v2 = *(const float4*)&wb[(kk + 2) * 100 + c];
                float4 v3 = *(const float4*)&wb[(kk + 3) * 100 + c];
                fma4(p0, a0.x, v0); fma4(p0, a0.y, v1); fma4(p0, a0.z, v2); fma4(p0, a0.w, v3);
                fma4(p1, a1.x, v0); fma4(p1, a1.y, v1); fma4(p1, a1.z, v2); fma4(p1, a1.w, v3);
            }
            if (tau == 4 || tau == 9) {
                const float* bb = (tau == 4) ? q_b : k_b;
                float* outp = (tau == 4) ? qt : ktb;
                float4 bias = *(const float4*)&bb[c];
                p0.x += bias.x; p0.y += bias.y; p0.z += bias.z; p0.w += bias.w;
                p1.x += bias.x; p1.y += bias.y; p1.z += bias.z; p1.w += bias.w;
                const int h = c / CDK, d = c % CDK;
                float4 rv[2] = { p0, p1 };
#pragma unroll
                for (int q = 0; q < 2; ++q) {
                    int row = r0 + rg * 2 + q;
                    int bidx = row >> 8, l = row & 255;
                    *(float4*)&outp[((size_t)(bidx * CH + h) * CL + l) * CDK + d] = rv[q];
                }
                p0 = make_float4(0.f, 0.f, 0.f, 0.f);
                p1 = make_float4(0.f, 0.f, 0.f, 0.f);
            }
        }
        __syncthreads();
    }
}

// ---------------------------------------------------------------------------
// k45: inline asp + softmax (adjS in LDS, adjW->global) + GCN0 + rank-1.
// Round-6 verified form (63.2 us).
// LESSON (do not revisit): the softmax h-loop has ZERO register headroom —
// kr prefetch (r10) or sm[] hoist / unroll (r5) spills pv[16] to scratch
// (+8MB WRITE_SIZE, +12us). Keep kr loads serial per head.
// ---------------------------------------------------------------------------
__global__ __launch_bounds__(256, 3) void k45_attn_gcn0(
    const float* __restrict__ qt, const float* __restrict__ ktb,
    const float* __restrict__ aspect_raw, const float* __restrict__ amask,
    const float* __restrict__ dense_w, const float* __restrict__ dense_b,
    const float* __restrict__ bias_m, const int* __restrict__ src_mask,
    const float* __restrict__ shortm, const float* __restrict__ Wx_w,
    const float* __restrict__ g, const float* __restrict__ W_w,
    const float* __restrict__ W_b, float* __restrict__ adjW,
    float* __restrict__ go1, float* __restrict__ t1, float* __restrict__ t2,
    float* __restrict__ gW2S)
{
    constexpr int ICH = 16;
    __shared__ float s_pool[16 * 260];
    __shared__ float s_w[2][3200];
    __shared__ float s_q[CH * 320];
    __shared__ float s_red[CH][64];
    __shared__ float s_was[5];
    __shared__ float s_aspb[20];
    __shared__ float s_w1[100], s_w2[100];
    __shared__ float s_g1row[16];

    const int b = blockIdx.x >> 4, ic = blockIdx.x & 15;
    const int i0 = ic * ICH;
    const int t = threadIdx.x, lane = t & 63, wid = t >> 6;
    const int j = t;

    if (t < 5) {
        float s = 0.f;
        for (int k2 = 0; k2 < 5; ++k2) s += Wx_w[t * 5 + k2];
        s_was[t] = s;
    }
    if (t < 100) {
        float a = 0.f, c2 = 0.f;
#pragma unroll
        for (int h = 0; h < 5; ++h) {
            a += Wx_w[(5 + t) * 5 + h];
            c2 += Wx_w[(105 + t) * 5 + h];
        }
        s_w1[t] = a; s_w2[t] = c2;
    }
    float wn = 0.f;
    if (t < 64) {
        float4 mv = ((const float4*)amask)[b * 64 + t];
        wn = mv.x + mv.y + mv.z + mv.w;
#pragma unroll
        for (int o = 32; o; o >>= 1) wn += __shfl_xor(wn, o);
    }
    if (t < 20) {
        float a = 0.f;
        for (int d = 0; d < CATT; ++d)
            a = fmaf(aspect_raw[b * CATT + d], dense_w[d * CDK + t], a);
        s_aspb[t] = a / wn + dense_b[t];
    }
    {
        const float* qbase = qt + (size_t)b * CH * CL * CDK + (size_t)i0 * CDK;
        for (int i = t; i < CH * 320; i += 256) {
            int h = i / 320, r = i % 320;
            s_q[i] = qbase[(size_t)h * CL * CDK + r];
        }
    }

    const bool masked = (src_mask[b * CL + j] == 0);
    const float bm = bias_m[0];
    const float rs20 = 0.223606797749978969f;

    float sm[ICH];
#pragma unroll
    for (int ii = 0; ii < ICH; ++ii)
        sm[ii] = shortm[(size_t)(b * CL + i0 + ii) * CL + j];

    float accS[ICH], accW[ICH];
#pragma unroll
    for (int ii = 0; ii < ICH; ++ii) { accS[ii] = 0.f; accW[ii] = 0.f; }

    __syncthreads();

    for (int h = 0; h < CH; ++h) {
        float4 kr[5];
        const float* kp = ktb + ((size_t)(b * CH + h) * CL + j) * CDK;
#pragma unroll
        for (int m = 0; m < 5; ++m) kr[m] = *(const float4*)(kp + 4 * m);
        const float was_h = s_was[h];
        float s = bm;
#pragma unroll
        for (int m = 0; m < 5; ++m) {
            s = fmaf(s_aspb[4 * m + 0], kr[m].x, s);
            s = fmaf(s_aspb[4 * m + 1], kr[m].y, s);
            s = fmaf(s_aspb[4 * m + 2], kr[m].z, s);
            s = fmaf(s_aspb[4 * m + 3], kr[m].w, s);
        }
        const float aspsc = tanhf(s);

        float pv[ICH];
#pragma unroll
        for (int ii = 0; ii < ICH; ++ii) {
            const float* qrow = &s_q[h * 320 + ii * CDK];
            float sc = 0.f;
#pragma unroll
            for (int m = 0; m < 5; ++m) {
                float4 q4 = *(const float4*)(qrow + 4 * m);
                sc = fmaf(q4.x, kr[m].x, sc);
                sc = fmaf(q4.y, kr[m].y, sc);
                sc = fmaf(q4.z, kr[m].z, sc);
                sc = fmaf(q4.w, kr[m].w, sc);
            }
            sc = fmaf(sc, rs20, aspsc) + sm[ii];
            float p = masked ? 0.f : __expf(sc);
            pv[ii] = p;
            float ssum = p;
#pragma unroll
            for (int o = 32; o; o >>= 1) ssum += __shfl_xor(ssum, o);
            if (lane == 0) s_red[h][ii * 4 + wid] = ssum;
        }
        __syncthreads();
#pragma unroll
        for (int ii = 0; ii < ICH; ++ii) {
            float tot = s_red[h][ii * 4 + 0] + s_red[h][ii * 4 + 1] +
                        s_red[h][ii * 4 + 2] + s_red[h][ii * 4 + 3];
            float pn = pv[ii] * __frcp_rn(tot);
            accS[ii] += pn;
            accW[ii] = fmaf(was_h, pn, accW[ii]);
        }
    }

#pragma unroll
    for (int ii = 0; ii < ICH; ++ii) {
        adjW[(size_t)(b * CL + i0 + ii) * CL + j] = accW[ii];
        s_pool[ii * 260 + j] = accS[ii];
    }

    // --- GEMM1: Ax = adjS_tile @ g (K=256, 8 tiles, global_load_lds staged)
    const int cg = t % 25, rg = t / 25;
    const int c = cg * 4;
    const float4* g4 = (const float4*)g + (size_t)b * 6400;
    gl2lds16(g4 + t,       &s_w[0][(t      ) * 4]);
    gl2lds16(g4 + t + 256, &s_w[0][(t + 256) * 4]);
    gl2lds16(g4 + t + 512, &s_w[0][(t + 512) * 4]);
    if (t < 32) gl2lds16(g4 + t + 768, &s_w[0][(t + 768) * 4]);
    __syncthreads();   // s_pool + tile0 visible

    float4 acc0 = make_float4(0.f, 0.f, 0.f, 0.f);
    float4 acc1 = make_float4(0.f, 0.f, 0.f, 0.f);
    for (int jt = 0; jt < 8; ++jt) {
        if (jt < 7) {
            const float4* src = g4 + (size_t)(jt + 1) * 800;
            float* wd = s_w[(jt + 1) & 1];
            gl2lds16(src + t,       wd + (t      ) * 4);
            gl2lds16(src + t + 256, wd + (t + 256) * 4);
            gl2lds16(src + t + 512, wd + (t + 512) * 4);
            if (t < 32) gl2lds16(src + t + 768, wd + (t + 768) * 4);
        }
        if (t < 200) {
            const float* wb = s_w[jt & 1];
#pragma unroll 2
            for (int kk = 0; kk < 32; kk += 4) {
                float4 a0 = *(const float4*)&s_pool[(rg * 2 + 0) * 260 + jt * 32 + kk];
                float4 a1 = *(const float4*)&s_pool[(rg * 2 + 1) * 260 + jt * 32 + kk];
                float4 v0 = *(const float4*)&wb[(kk + 0) * 100 + c];
                float4 v1 = *(const float4*)&wb[(kk + 1) * 100 + c];
                float4 v2 = *(const float4*)&wb[(kk + 2) * 100 + c];
                float4 v3 = *(const float4*)&wb[(kk + 3) * 100 + c];
                fma4(acc0, a0.x, v0); fma4(acc0, a0.y, v1); fma4(acc0, a0.z, v2); fma4(acc0, a0.w, v3);
                fma4(acc1, a1.x, v0); fma4(acc1, a1.y, v1); fma4(acc1, a1.z, v2); fma4(acc1, a1.w, v3);
            }
        }
        __syncthreads();
    }

    // s_ax overlay + W_w tile0 async stage
    float* s_ax = s_pool;
    if (t < 200) {
        float4 r;
        r.x = acc0.x * 0.2f; r.y = acc0.y * 0.2f; r.z = acc0.z * 0.2f; r.w = acc0.w * 0.2f;
        *(float4*)&s_ax[(rg * 2 + 0) * 108 + c] = r;
        r.x = acc1.x * 0.2f; r.y = acc1.y * 0.2f; r.z = acc1.z * 0.2f; r.w = acc1.w * 0.2f;
        *(float4*)&s_ax[(rg * 2 + 1) * 108 + c] = r;
    }
    const float4* ww4 = (const float4*)W_w;
    gl2lds16(ww4 + t, &s_w[0][t * 4]);
    if (t < 244) gl2lds16(ww4 + t + 256, &s_w[0][(t + 256) * 4]);
    __syncthreads();

    // --- GEMM2: go1 = relu(Ax @ W_w + W_b), 5 tiles
    float4 o0 = make_float4(0.f, 0.f, 0.f, 0.f);
    float4 o1 = make_float4(0.f, 0.f, 0.f, 0.f);
    for (int wt = 0; wt < 5; ++wt) {
        if (wt < 4) {
            const float4* src = ww4 + (size_t)(wt + 1) * 500;
            float* wd = s_w[(wt + 1) & 1];
            gl2lds16(src + t, wd + t * 4);
            if (t < 244) gl2lds16(src + t + 256, wd + (t + 256) * 4);
        }
        if (t < 200) {
            const float* wb = s_w[wt & 1];
            const int kb = wt * 20;
#pragma unroll 2
            for (int kk = 0; kk < 20; kk += 4) {
                float4 a0 = *(const float4*)&s_ax[(rg * 2 + 0) * 108 + kb + kk];
                float4 a1 = *(const float4*)&s_ax[(rg * 2 + 1) * 108 + kb + kk];
                float4 v0 = *(const float4*)&wb[(kk + 0) * 100 + c];
                float4 v1 = *(const float4*)&wb[(kk + 1) * 100 + c];
                float4 v2 = *(const float4*)&wb[(kk + 2) * 100 + c];
                float4 v3 = *(const float4*)&wb[(kk + 3) * 100 + c];
                fma4(o0, a0.x, v0); fma4(o0, a0.y, v1); fma4(o0, a0.z, v2); fma4(o0, a0.w, v3);
                fma4(o1, a1.x, v0); fma4(o1, a1.y, v1); fma4(o1, a1.z, v2); fma4(o1, a1.w, v3);
            }
        }
        __syncthreads();
    }

    float* s_go = s_pool + 1728;
    if (t < 200) {
        float4 bias = *(const float4*)&W_b[c];
        o0.x = fmaxf(o0.x + bias.x, 0.f); o0.y = fmaxf(o0.y + bias.y, 0.f);
        o0.z = fmaxf(o0.z + bias.z, 0.f); o0.w = fmaxf(o0.w + bias.w, 0.f);
        o1.x = fmaxf(o1.x + bias.x, 0.f); o1.y = fmaxf(o1.y + bias.y, 0.f);
        o1.z = fmaxf(o1.z + bias.z, 0.f); o1.w = fmaxf(o1.w + bias.w, 0.f);
        *(float4*)&go1[(size_t)(b * CL + i0 + rg * 2 + 0) * CATT + c] = o0;
        *(float4*)&go1[(size_t)(b * CL + i0 + rg * 2 + 1) * CATT + c] = o1;
        *(float4*)&s_go[(rg * 2 + 0) * 104 + c] = o0;
        *(float4*)&s_go[(rg * 2 + 1) * 104 + c] = o1;
    }
    __syncthreads();

    if (t < 128) {
        int r = t >> 3, seg = t & 7;
        int e0 = seg * 13, e1 = e0 + 13 < 100 ? e0 + 13 : 100;
        float a = 0.f, c2 = 0.f;
        for (int e = e0; e < e1; ++e) {
            float v = s_go[r * 104 + e];
            a = fmaf(v, s_w1[e], a);
            c2 = fmaf(v, s_w2[e], c2);
        }
        a += __shfl_xor(a, 1); a += __shfl_xor(a, 2); a += __shfl_xor(a, 4);
        c2 += __shfl_xor(c2, 1); c2 += __shfl_xor(c2, 2); c2 += __shfl_xor(c2, 4);
        if (seg == 0) {
            s_g1row[r] = a;
            gW2S[b * CL + i0 + r] = c2;
        }
    }
    __syncthreads();

    if (t < 100) {
        float a = 0.f, s2 = 0.f;
#pragma unroll
        for (int r = 0; r < 16; ++r) {
            float v = s_go[r * 104 + t];
            a = fmaf(s_g1row[r], v, a);
            s2 += v;
        }
        atomicAdd(&t1[b * CATT + t], a);
        atomicAdd(&t2[b * CATT + t], s2);
    }
}

// ---------------------------------------------------------------------------
// k7: GCN1 with rank-1 corrections; pooled epilogue -> out1_raw atomics.
// Round-6 verified form (gl2lds staging incl. adjW tile).
// ---------------------------------------------------------------------------
__global__ __launch_bounds__(256, 3) void k7_gcn1(
    const float* __restrict__ adjW, const float* __restrict__ go1,
    const float* __restrict__ W_w, const float* __restrict__ W_b,
    const float* __restrict__ t1, const float* __restrict__ t2,
    const float* __restrict__ gW2S, const float* __restrict__ Wx_b,
    const float* __restrict__ amask, float* __restrict__ out1_raw)
{
    __shared__ float s_pool[16 * 260];
    __shared__ float s_w[2][3200];
    const int b = blockIdx.x >> 4, ic = blockIdx.x & 15;
    const int i0 = ic * 16;
    const int t = threadIdx.x;

    {
        const float4* asrc = (const float4*)adjW + (size_t)(b * CL + i0) * 64;
#pragma unroll
        for (int m = 0; m < 4; ++m) {
            int i = t + 256 * m;
            gl2lds16(asrc + i, &s_pool[(i >> 6) * 260 + (i & 63) * 4]);
        }
    }
    const int cg = t % 25, rg = t / 25;
    const int c = cg * 4;
    const float4* g4 = (const float4*)go1 + (size_t)b * 6400;
    gl2lds16(g4 + t,       &s_w[0][(t      ) * 4]);
    gl2lds16(g4 + t + 256, &s_w[0][(t + 256) * 4]);
    gl2lds16(g4 + t + 512, &s_w[0][(t + 512) * 4]);
    if (t < 32) gl2lds16(g4 + t + 768, &s_w[0][(t + 768) * 4]);
    __syncthreads();

    float4 acc0 = make_float4(0.f, 0.f, 0.f, 0.f);
    float4 acc1 = make_float4(0.f, 0.f, 0.f, 0.f);
    for (int jt = 0; jt < 8; ++jt) {
        if (jt < 7) {
            const float4* src = g4 + (size_t)(jt + 1) * 800;
            float* wd = s_w[(jt + 1) & 1];
            gl2lds16(src + t,       wd + (t      ) * 4);
            gl2lds16(src + t + 256, wd + (t + 256) * 4);
            gl2lds16(src + t + 512, wd + (t + 512) * 4);
            if (t < 32) gl2lds16(src + t + 768, wd + (t + 768) * 4);
        }
        if (t < 200) {
            const float* wb = s_w[jt & 1];
#pragma unroll 2
            for (int kk = 0; kk < 32; kk += 4) {
                float4 a0 = *(const float4*)&s_pool[(rg * 2 + 0) * 260 + jt * 32 + kk];
                float4 a1 = *(const float4*)&s_pool[(rg * 2 + 1) * 260 + jt * 32 + kk];
                float4 v0 = *(const float4*)&wb[(kk + 0) * 100 + c];
                float4 v1 = *(const float4*)&wb[(kk + 1) * 100 + c];
                float4 v2 = *(const float4*)&wb[(kk + 2) * 100 + c];
                float4 v3 = *(const float4*)&wb[(kk + 3) * 100 + c];
                fma4(acc0, a0.x, v0); fma4(acc0, a0.y, v1); fma4(acc0, a0.z, v2); fma4(acc0, a0.w, v3);
                fma4(acc1, a1.x, v0); fma4(acc1, a1.y, v1); fma4(acc1, a1.z, v2); fma4(acc1, a1.w, v3);
            }
        }
        __syncthreads();
    }

    float* s_ax = s_pool;
    if (t < 200) {
        float wxbs = Wx_b[0] + Wx_b[1] + Wx_b[2] + Wx_b[3] + Wx_b[4];
        float4 t1v = *(const float4*)&t1[b * CATT + c];
        float4 t2v = *(const float4*)&t2[b * CATT + c];
        float gw0 = gW2S[b * CL + i0 + rg * 2 + 0] + wxbs;
        float gw1 = gW2S[b * CL + i0 + rg * 2 + 1] + wxbs;
        float4 r;
        r.x = (acc0.x + t1v.x + gw0 * t2v.x) * 0.2f;
        r.y = (acc0.y + t1v.y + gw0 * t2v.y) * 0.2f;
        r.z = (acc0.z + t1v.z + gw0 * t2v.z) * 0.2f;
        r.w = (acc0.w + t1v.w + gw0 * t2v.w) * 0.2f;
        *(float4*)&s_ax[(rg * 2 + 0) * 108 + c] = r;
        r.x = (acc1.x + t1v.x + gw1 * t2v.x) * 0.2f;
        r.y = (acc1.y + t1v.y + gw1 * t2v.y) * 0.2f;
        r.z = (acc1.z + t1v.z + gw1 * t2v.z) * 0.2f;
        r.w = (acc1.w + t1v.w + gw1 * t2v.w) * 0.2f;
        *(float4*)&s_ax[(rg * 2 + 1) * 108 + c] = r;
    }
    const float4* ww4 = (const float4*)W_w;
    gl2lds16(ww4 + t, &s_w[0][t * 4]);
    if (t < 244) gl2lds16(ww4 + t + 256, &s_w[0][(t + 256) * 4]);
    __syncthreads();

    float4 o0 = make_float4(0.f, 0.f, 0.f, 0.f);
    float4 o1 = make_float4(0.f, 0.f, 0.f, 0.f);
    for (int wt = 0; wt < 5; ++wt) {
        if (wt < 4) {
            const float4* src = ww4 + (size_t)(wt + 1) * 500;
            float* wd = s_w[(wt + 1) & 1];
            gl2lds16(src + t, wd + t * 4);
            if (t < 244) gl2lds16(src + t + 256, wd + (t + 256) * 4);
        }
        if (t < 200) {
            const float* wb = s_w[wt & 1];
            const int kb = wt * 20;
#pragma unroll 2
            for (int kk = 0; kk < 20; kk += 4) {
                float4 a0 = *(const float4*)&s_ax[(rg * 2 + 0) * 108 + kb + kk];
                float4 a1 = *(const float4*)&s_ax[(rg * 2 + 1) * 108 + kb + kk];
                float4 v0 = *(const float4*)&wb[(kk + 0) * 100 + c];
                float4 v1 = *(const float4*)&wb[(kk + 1) * 100 + c];
                float4 v2 = *(const float4*)&wb[(kk + 2) * 100 + c];
                float4 v3 = *(const float4*)&wb[(kk + 3) * 100 + c];
                fma4(o0, a0.x, v0); fma4(o0, a0.y, v1); fma4(o0, a0.z, v2); fma4(o0, a0.w, v3);
                fma4(o1, a1.x, v0); fma4(o1, a1.y, v1); fma4(o1, a1.z, v2); fma4(o1, a1.w, v3);
            }
        }
        __syncthreads();
    }

    if (t < 200) {
        float4 bias = *(const float4*)&W_b[c];
        o0.x = fmaxf(o0.x + bias.x, 0.f); o0.y = fmaxf(o0.y + bias.y, 0.f);
        o0.z = fmaxf(o0.z + bias.z, 0.f); o0.w = fmaxf(o0.w + bias.w, 0.f);
        o1.x = fmaxf(o1.x + bias.x, 0.f); o1.y = fmaxf(o1.y + bias.y, 0.f);
        o1.z = fmaxf(o1.z + bias.z, 0.f); o1.w = fmaxf(o1.w + bias.w, 0.f);
        float4 ov[2] = { o0, o1 };
#pragma unroll
        for (int q = 0; q < 2; ++q) {
            int row = b * CL + i0 + rg * 2 + q;
            float m = amask[row];
            if (m != 0.f) {
                atomicAdd(&out1_raw[b * CATT + c + 0], m * ov[q].x);
                atomicAdd(&out1_raw[b * CATT + c + 1], m * ov[q].y);
                atomicAdd(&out1_raw[b * CATT + c + 2], m * ov[q].z);
                atomicAdd(&out1_raw[b * CATT + c + 3], m * ov[q].w);
            }
        }
    }
}

// ---------------------------------------------------------------------------
__global__ __launch_bounds__(64) void k8_small(
    const float* __restrict__ out1_raw, const float* __restrict__ amask,
    const float* __restrict__ clf_w, const float* __restrict__ clf_b,
    float* __restrict__ out)
{
    const int b = blockIdx.x, t = threadIdx.x;
    float4 mv = ((const float4*)amask)[b * 64 + t];
    float wn = mv.x + mv.y + mv.z + mv.w;
#pragma unroll
    for (int o = 32; o; o >>= 1) wn += __shfl_xor(wn, o);
    if (t < 3) {
        float rwn = 1.f / wn;
        float a = clf_b[t];
        for (int d = 0; d < CATT; ++d)
            a = fmaf(out1_raw[b * CATT + d] * rwn, clf_w[d * 3 + t], a);
        out[b * 3 + t] = a;
    }
}

// ---------------------------------------------------------------------------
extern "C" void kernel_launch(void* const* d_in, const int* in_sizes, int n_in,
                              void* d_out, int out_size, void* d_ws, size_t ws_size,
                              hipStream_t stream) {
    const float* seq     = (const float*)d_in[0];
    const int*   srcm    = (const int*)d_in[1];
    const float* amask   = (const float*)d_in[2];
    const float* shortm  = (const float*)d_in[3];
    const float* ln_a    = (const float*)d_in[4];
    const float* ln_b    = (const float*)d_in[5];
    const float* Wxx_w   = (const float*)d_in[6];
    const float* Wxx_b   = (const float*)d_in[7];
    const float* q_w     = (const float*)d_in[8];
    const float* q_b     = (const float*)d_in[9];
    const float* k_w     = (const float*)d_in[10];
    const float* k_b     = (const float*)d_in[11];
    const float* dense_w = (const float*)d_in[12];
    const float* dense_b = (const float*)d_in[13];
    const float* bias_m  = (const float*)d_in[14];
    const float* W_w     = (const float*)d_in[15];
    const float* W_b     = (const float*)d_in[16];
    const float* Wx_w    = (const float*)d_in[17];
    const float* Wx_b    = (const float*)d_in[18];
    const float* clf_w   = (const float*)d_in[19];
    const float* clf_b   = (const float*)d_in[20];
    float* out = (float*)d_out;

    float* ws         = (float*)d_ws;
    float* g          = ws;
    float* qt         = g + 819200;
    float* ktb        = qt + 819200;
    float* go1        = ktb + 819200;
    float* adjW       = go1 + 819200;
    float* aspect_raw = adjW + 2097152;
    float* t1         = aspect_raw + 3200;
    float* t2         = t1 + 3200;
    float* out1_raw   = t2 + 3200;
    float* gW2S       = out1_raw + 3200;

    hipMemsetAsync(aspect_raw, 0, 4 * 3200 * sizeof(float), stream);
    hipLaunchKernelGGL(k1_fused, dim3(512), dim3(256), 0, stream, seq, ln_a, ln_b,
                       Wxx_w, Wxx_b, q_w, q_b, k_w, k_b, amask, g, qt, ktb, aspect_raw);
    hipLaunchKernelGGL(k45_attn_gcn0, dim3(512), dim3(256), 0, stream,
                       qt, ktb, aspect_raw, amask, dense_w, dense_b, bias_m, srcm,
                       shortm, Wx_w, g, W_w, W_b, adjW, go1, t1, t2, gW2S);
    hipLaunchKernelGGL(k7_gcn1, dim3(512), dim3(256), 0, stream,
                       adjW, go1, W_w, W_b, t1, t2, gW2S, Wx_b, amask, out1_raw);
    hipLaunchKernelGGL(k8_small, dim3(32), dim3(64), 0, stream,
                       out1_raw, amask, clf_w, clf_b, out);
}

// Round 12
// 240.195 us; speedup vs baseline: 1.1135x; 1.0016x over previous
//
#include <hip/hip_runtime.h>
#include <math.h>

constexpr int CL = 256;
constexpr int CD = 768;
constexpr int CATT = 100;
constexpr int CH = 5;
constexpr int CDK = 20;

__device__ __forceinline__ void fma4(float4& a, float s, const float4& w) {
    a.x = fmaf(s, w.x, a.x);
    a.y = fmaf(s, w.y, a.y);
    a.z = fmaf(s, w.z, a.z);
    a.w = fmaf(s, w.w, a.w);
}

// Async global->LDS, 16B per lane (validated round 6).
__device__ __forceinline__ void gl2lds16(const void* gsrc, void* ldst) {
    __builtin_amdgcn_global_load_lds(
        (const __attribute__((address_space(1))) void*)gsrc,
        (__attribute__((address_space(3))) void*)ldst, 16, 0, 0);
}

// XCD-aware block remap (bijective): consecutive blockIdx round-robin over
// the 8 XCDs, so mapping batch = (blk&7)*4 + ((blk>>3)>>4) puts all 16
// blocks of a batch — and the SAME batch across k1/k45/k7 — on one XCD.
// Batch intermediates (g/qt/ktb/go1/adjW panels, ~100KB each, 16x reuse)
// then stay in that XCD's 4MB L2 from producer to consumer. Pure speed
// heuristic; correctness is mapping-independent (G16).
__device__ __forceinline__ void xcd_map(int blk, int& batch, int& ic) {
    const int xcd = blk & 7, slot = blk >> 3;
    batch = xcd * 4 + (slot >> 4);
    ic = slot & 15;
}

// ---------------------------------------------------------------------------
// k1: LN + g = xn@Wxx + b, q/k GEMMs, masked aspect pooling (atomics).
// Round-6 verified form (65.3 us) + XCD remap of the row-tile index.
// LESSONS (do not revisit): 4x4/100-thread blocking regresses (r9 —
// latency-bound, TLP > per-FLOP LDS traffic); unroll/prefetch spills (r5).
// ---------------------------------------------------------------------------
__global__ __launch_bounds__(256, 3) void k1_fused(
    const float* __restrict__ x, const float* __restrict__ ln_a,
    const float* __restrict__ ln_b, const float* __restrict__ Wxx_w,
    const float* __restrict__ Wxx_b, const float* __restrict__ q_w,
    const float* __restrict__ q_b, const float* __restrict__ k_w,
    const float* __restrict__ k_b, const float* __restrict__ amask,
    float* __restrict__ g, float* __restrict__ qt, float* __restrict__ ktb,
    float* __restrict__ aspect_raw)
{
    __shared__ float s_w[2][3200];
    __shared__ float s_xn[2][16 * 36];
    __shared__ float s_gt[16 * 100];
    __shared__ float s_ln[1536];
    __shared__ float s_mean[16], s_rinv[16];

    const int t = threadIdx.x;
    int batchM, icM;
    xcd_map(blockIdx.x, batchM, icM);
    const int r0 = batchM * 256 + icM * 16;
    const int wid = t >> 6, lane = t & 63;

    if (t < 192) {
        ((float4*)s_ln)[t] = ((const float4*)ln_a)[t];
        ((float4*)(s_ln + 768))[t] = ((const float4*)ln_b)[t];
    }

    for (int rr = wid * 4; rr < wid * 4 + 4; ++rr) {
        const float* xr = x + (size_t)(r0 + rr) * CD;
        float xv[12];
        float s = 0.f;
#pragma unroll
        for (int m = 0; m < 12; ++m) { xv[m] = xr[lane + 64 * m]; s += xv[m]; }
#pragma unroll
        for (int o = 32; o; o >>= 1) s += __shfl_xor(s, o);
        float mean = s * (1.0f / 768.0f);
        float sq = 0.f;
#pragma unroll
        for (int m = 0; m < 12; ++m) { float d = xv[m] - mean; sq = fmaf(d, d, sq); }
#pragma unroll
        for (int o = 32; o; o >>= 1) sq += __shfl_xor(sq, o);
        if (lane == 0) {
            s_mean[rr] = mean;
            s_rinv[rr] = 1.0f / (sqrtf(sq * (1.0f / 767.0f)) + 1e-6f);
        }
    }

    const float4* wsrc = (const float4*)Wxx_w;
    gl2lds16(wsrc + t,       &s_w[0][(t      ) * 4]);
    gl2lds16(wsrc + t + 256, &s_w[0][(t + 256) * 4]);
    gl2lds16(wsrc + t + 512, &s_w[0][(t + 512) * 4]);
    if (t < 32) gl2lds16(wsrc + t + 768, &s_w[0][(t + 768) * 4]);
    const int rA = t >> 5, cA = t & 31;
    float xa = x[(size_t)(r0 + rA) * CD + cA];
    float xb = x[(size_t)(r0 + rA + 8) * CD + cA];

    __syncthreads();

    {
        float la = s_ln[cA], lbv = s_ln[768 + cA];
        s_xn[0][rA * 36 + cA] = fmaf(la, (xa - s_mean[rA]) * s_rinv[rA], lbv);
        s_xn[0][(rA + 8) * 36 + cA] = fmaf(la, (xb - s_mean[rA + 8]) * s_rinv[rA + 8], lbv);
    }
    __syncthreads();

    const int cg = t % 25, rg = t / 25;
    const int c = cg * 4;
    float4 acc0 = make_float4(0.f, 0.f, 0.f, 0.f);
    float4 acc1 = make_float4(0.f, 0.f, 0.f, 0.f);

    for (int kt = 0; kt < 24; ++kt) {
        if (kt < 23) {
            const float4* ws = wsrc + (size_t)(kt + 1) * 800;
            float* wd = s_w[(kt + 1) & 1];
            gl2lds16(ws + t,       wd + (t      ) * 4);
            gl2lds16(ws + t + 256, wd + (t + 256) * 4);
            gl2lds16(ws + t + 512, wd + (t + 512) * 4);
            if (t < 32) gl2lds16(ws + t + 768, wd + (t + 768) * 4);
            int gc = (kt + 1) * 32 + cA;
            xa = x[(size_t)(r0 + rA) * CD + gc];
            xb = x[(size_t)(r0 + rA + 8) * CD + gc];
        }
        if (t < 200) {
            const float* wb = s_w[kt & 1];
            const float* xbuf = s_xn[kt & 1];
#pragma unroll 2
            for (int kk = 0; kk < 32; kk += 4) {
                float4 a0 = *(const float4*)&xbuf[(rg * 2 + 0) * 36 + kk];
                float4 a1 = *(const float4*)&xbuf[(rg * 2 + 1) * 36 + kk];
                float4 v0 = *(const float4*)&wb[(kk + 0) * 100 + c];
                float4 v1 = *(const float4*)&wb[(kk + 1) * 100 + c];
                float4 v2 = *(const float4*)&wb[(kk + 2) * 100 + c];
                float4 v3 = *(const float4*)&wb[(kk + 3) * 100 + c];
                fma4(acc0, a0.x, v0); fma4(acc0, a0.y, v1); fma4(acc0, a0.z, v2); fma4(acc0, a0.w, v3);
                fma4(acc1, a1.x, v0); fma4(acc1, a1.y, v1); fma4(acc1, a1.z, v2); fma4(acc1, a1.w, v3);
            }
        }
        if (kt < 23) {
            int gc = (kt + 1) * 32 + cA;
            float la = s_ln[gc], lbv = s_ln[768 + gc];
            float* xd = s_xn[(kt + 1) & 1];
            xd[rA * 36 + cA] = fmaf(la, (xa - s_mean[rA]) * s_rinv[rA], lbv);
            xd[(rA + 8) * 36 + cA] = fmaf(la, (xb - s_mean[rA + 8]) * s_rinv[rA + 8], lbv);
        }
        __syncthreads();
    }

    if (t < 200) {
        float4 bias = *(const float4*)&Wxx_b[c];
        float4 rv0, rv1;
        rv0.x = acc0.x + bias.x; rv0.y = acc0.y + bias.y; rv0.z = acc0.z + bias.z; rv0.w = acc0.w + bias.w;
        rv1.x = acc1.x + bias.x; rv1.y = acc1.y + bias.y; rv1.z = acc1.z + bias.z; rv1.w = acc1.w + bias.w;
        float4 rv[2] = { rv0, rv1 };
#pragma unroll
        for (int q = 0; q < 2; ++q) {
            int row = r0 + rg * 2 + q;
            *(float4*)&g[(size_t)row * CATT + c] = rv[q];
            *(float4*)&s_gt[(rg * 2 + q) * 100 + c] = rv[q];
            float m = amask[row];
            if (m != 0.f) {
                int b = row >> 8;
                atomicAdd(&aspect_raw[b * CATT + c + 0], m * rv[q].x);
                atomicAdd(&aspect_raw[b * CATT + c + 1], m * rv[q].y);
                atomicAdd(&aspect_raw[b * CATT + c + 2], m * rv[q].z);
                atomicAdd(&aspect_raw[b * CATT + c + 3], m * rv[q].w);
            }
        }
    }

    const float4* qw4 = (const float4*)q_w;
    const float4* kw4 = (const float4*)k_w;
    gl2lds16(qw4 + t, &s_w[0][t * 4]);
    if (t < 244) gl2lds16(qw4 + t + 256, &s_w[0][(t + 256) * 4]);
    __syncthreads();

    float4 p0 = make_float4(0.f, 0.f, 0.f, 0.f);
    float4 p1 = make_float4(0.f, 0.f, 0.f, 0.f);
    for (int tau = 0; tau < 10; ++tau) {
        if (tau < 9) {
            const float4* src = (tau + 1 < 5) ? qw4 + (size_t)(tau + 1) * 500
                                              : kw4 + (size_t)(tau - 4) * 500;
            float* wd = s_w[(tau + 1) & 1];
            gl2lds16(src + t, wd + t * 4);
            if (t < 244) gl2lds16(src + t + 256, wd + (t + 256) * 4);
        }
        if (t < 200) {
            const float* wb = s_w[tau & 1];
            const int kb = (tau % 5) * 20;
#pragma unroll 2
            for (int kk = 0; kk < 20; kk += 4) {
                float4 a0 = *(const float4*)&s_gt[(rg * 2 + 0) * 100 + kb + kk];
                float4 a1 = *(const float4*)&s_gt[(rg * 2 + 1) * 100 + kb + kk];
                float4 v0 = *(const float4*)&wb[(kk + 0) * 100 + c];
                float4 v1 = *(const float4*)&wb[(kk + 1) * 100 + c];
                float4 v2 = *(const float4*)&wb[(kk + 2) * 100 + c];
                float4 v3 = *(const float4*)&wb[(kk + 3) * 100 + c];
                fma4(p0, a0.x, v0); fma4(p0, a0.y, v1); fma4(p0, a0.z, v2); fma4(p0, a0.w, v3);
                fma4(p1, a1.x, v0); fma4(p1, a1.y, v1); fma4(p1, a1.z, v2); fma4(p1, a1.w, v3);
            }
            if (tau == 4 || tau == 9) {
                const float* bb = (tau == 4) ? q_b : k_b;
                float* outp = (tau == 4) ? qt : ktb;
                float4 bias = *(const float4*)&bb[c];
                p0.x += bias.x; p0.y += bias.y; p0.z += bias.z; p0.w += bias.w;
                p1.x += bias.x; p1.y += bias.y; p1.z += bias.z; p1.w += bias.w;
                const int h = c / CDK, d = c % CDK;
                float4 rv[2] = { p0, p1 };
#pragma unroll
                for (int q = 0; q < 2; ++q) {
                    int row = r0 + rg * 2 + q;
                    int bidx = row >> 8, l = row & 255;
                    *(float4*)&outp[((size_t)(bidx * CH + h) * CL + l) * CDK + d] = rv[q];
                }
                p0 = make_float4(0.f, 0.f, 0.f, 0.f);
                p1 = make_float4(0.f, 0.f, 0.f, 0.f);
            }
        }
        __syncthreads();
    }
}

// ---------------------------------------------------------------------------
// k45: inline asp + softmax (adjS in LDS, adjW->global) + GCN0 + rank-1.
// Round-6 verified form (63.2 us) + XCD remap of (b, ic).
// LESSON (do not revisit): softmax h-loop has ZERO register headroom — kr
// prefetch (r10) or sm[] hoist/unroll (r5) spills pv[16] (+8MB WRITE, +12us).
// ---------------------------------------------------------------------------
__global__ __launch_bounds__(256, 3) void k45_attn_gcn0(
    const float* __restrict__ qt, const float* __restrict__ ktb,
    const float* __restrict__ aspect_raw, const float* __restrict__ amask,
    const float* __restrict__ dense_w, const float* __restrict__ dense_b,
    const float* __restrict__ bias_m, const int* __restrict__ src_mask,
    const float* __restrict__ shortm, const float* __restrict__ Wx_w,
    const float* __restrict__ g, const float* __restrict__ W_w,
    const float* __restrict__ W_b, float* __restrict__ adjW,
    float* __restrict__ go1, float* __restrict__ t1, float* __restrict__ t2,
    float* __restrict__ gW2S)
{
    constexpr int ICH = 16;
    __shared__ float s_pool[16 * 260];
    __shared__ float s_w[2][3200];
    __shared__ float s_q[CH * 320];
    __shared__ float s_red[CH][64];
    __shared__ float s_was[5];
    __shared__ float s_aspb[20];
    __shared__ float s_w1[100], s_w2[100];
    __shared__ float s_g1row[16];

    int b, ic;
    xcd_map(blockIdx.x, b, ic);
    const int i0 = ic * ICH;
    const int t = threadIdx.x, lane = t & 63, wid = t >> 6;
    const int j = t;

    if (t < 5) {
        float s = 0.f;
        for (int k2 = 0; k2 < 5; ++k2) s += Wx_w[t * 5 + k2];
        s_was[t] = s;
    }
    if (t < 100) {
        float a = 0.f, c2 = 0.f;
#pragma unroll
        for (int h = 0; h < 5; ++h) {
            a += Wx_w[(5 + t) * 5 + h];
            c2 += Wx_w[(105 + t) * 5 + h];
        }
        s_w1[t] = a; s_w2[t] = c2;
    }
    float wn = 0.f;
    if (t < 64) {
        float4 mv = ((const float4*)amask)[b * 64 + t];
        wn = mv.x + mv.y + mv.z + mv.w;
#pragma unroll
        for (int o = 32; o; o >>= 1) wn += __shfl_xor(wn, o);
    }
    if (t < 20) {
        float a = 0.f;
        for (int d = 0; d < CATT; ++d)
            a = fmaf(aspect_raw[b * CATT + d], dense_w[d * CDK + t], a);
        s_aspb[t] = a / wn + dense_b[t];
    }
    {
        const float* qbase = qt + (size_t)b * CH * CL * CDK + (size_t)i0 * CDK;
        for (int i = t; i < CH * 320; i += 256) {
            int h = i / 320, r = i % 320;
            s_q[i] = qbase[(size_t)h * CL * CDK + r];
        }
    }

    const bool masked = (src_mask[b * CL + j] == 0);
    const float bm = bias_m[0];
    const float rs20 = 0.223606797749978969f;

    float sm[ICH];
#pragma unroll
    for (int ii = 0; ii < ICH; ++ii)
        sm[ii] = shortm[(size_t)(b * CL + i0 + ii) * CL + j];

    float accS[ICH], accW[ICH];
#pragma unroll
    for (int ii = 0; ii < ICH; ++ii) { accS[ii] = 0.f; accW[ii] = 0.f; }

    __syncthreads();

    for (int h = 0; h < CH; ++h) {
        float4 kr[5];
        const float* kp = ktb + ((size_t)(b * CH + h) * CL + j) * CDK;
#pragma unroll
        for (int m = 0; m < 5; ++m) kr[m] = *(const float4*)(kp + 4 * m);
        const float was_h = s_was[h];
        float s = bm;
#pragma unroll
        for (int m = 0; m < 5; ++m) {
            s = fmaf(s_aspb[4 * m + 0], kr[m].x, s);
            s = fmaf(s_aspb[4 * m + 1], kr[m].y, s);
            s = fmaf(s_aspb[4 * m + 2], kr[m].z, s);
            s = fmaf(s_aspb[4 * m + 3], kr[m].w, s);
        }
        const float aspsc = tanhf(s);

        float pv[ICH];
#pragma unroll
        for (int ii = 0; ii < ICH; ++ii) {
            const float* qrow = &s_q[h * 320 + ii * CDK];
            float sc = 0.f;
#pragma unroll
            for (int m = 0; m < 5; ++m) {
                float4 q4 = *(const float4*)(qrow + 4 * m);
                sc = fmaf(q4.x, kr[m].x, sc);
                sc = fmaf(q4.y, kr[m].y, sc);
                sc = fmaf(q4.z, kr[m].z, sc);
                sc = fmaf(q4.w, kr[m].w, sc);
            }
            sc = fmaf(sc, rs20, aspsc) + sm[ii];
            float p = masked ? 0.f : __expf(sc);
            pv[ii] = p;
            float ssum = p;
#pragma unroll
            for (int o = 32; o; o >>= 1) ssum += __shfl_xor(ssum, o);
            if (lane == 0) s_red[h][ii * 4 + wid] = ssum;
        }
        __syncthreads();
#pragma unroll
        for (int ii = 0; ii < ICH; ++ii) {
            float tot = s_red[h][ii * 4 + 0] + s_red[h][ii * 4 + 1] +
                        s_red[h][ii * 4 + 2] + s_red[h][ii * 4 + 3];
            float pn = pv[ii] * __frcp_rn(tot);
            accS[ii] += pn;
            accW[ii] = fmaf(was_h, pn, accW[ii]);
        }
    }

#pragma unroll
    for (int ii = 0; ii < ICH; ++ii) {
        adjW[(size_t)(b * CL + i0 + ii) * CL + j] = accW[ii];
        s_pool[ii * 260 + j] = accS[ii];
    }

    // --- GEMM1: Ax = adjS_tile @ g (K=256, 8 tiles, global_load_lds staged)
    const int cg = t % 25, rg = t / 25;
    const int c = cg * 4;
    const float4* g4 = (const float4*)g + (size_t)b * 6400;
    gl2lds16(g4 + t,       &s_w[0][(t      ) * 4]);
    gl2lds16(g4 + t + 256, &s_w[0][(t + 256) * 4]);
    gl2lds16(g4 + t + 512, &s_w[0][(t + 512) * 4]);
    if (t < 32) gl2lds16(g4 + t + 768, &s_w[0][(t + 768) * 4]);
    __syncthreads();   // s_pool + tile0 visible

    float4 acc0 = make_float4(0.f, 0.f, 0.f, 0.f);
    float4 acc1 = make_float4(0.f, 0.f, 0.f, 0.f);
    for (int jt = 0; jt < 8; ++jt) {
        if (jt < 7) {
            const float4* src = g4 + (size_t)(jt + 1) * 800;
            float* wd = s_w[(jt + 1) & 1];
            gl2lds16(src + t,       wd + (t      ) * 4);
            gl2lds16(src + t + 256, wd + (t + 256) * 4);
            gl2lds16(src + t + 512, wd + (t + 512) * 4);
            if (t < 32) gl2lds16(src + t + 768, wd + (t + 768) * 4);
        }
        if (t < 200) {
            const float* wb = s_w[jt & 1];
#pragma unroll 2
            for (int kk = 0; kk < 32; kk += 4) {
                float4 a0 = *(const float4*)&s_pool[(rg * 2 + 0) * 260 + jt * 32 + kk];
                float4 a1 = *(const float4*)&s_pool[(rg * 2 + 1) * 260 + jt * 32 + kk];
                float4 v0 = *(const float4*)&wb[(kk + 0) * 100 + c];
                float4 v1 = *(const float4*)&wb[(kk + 1) * 100 + c];
                float4 v2 = *(const float4*)&wb[(kk + 2) * 100 + c];
                float4 v3 = *(const float4*)&wb[(kk + 3) * 100 + c];
                fma4(acc0, a0.x, v0); fma4(acc0, a0.y, v1); fma4(acc0, a0.z, v2); fma4(acc0, a0.w, v3);
                fma4(acc1, a1.x, v0); fma4(acc1, a1.y, v1); fma4(acc1, a1.z, v2); fma4(acc1, a1.w, v3);
            }
        }
        __syncthreads();
    }

    // s_ax overlay + W_w tile0 async stage
    float* s_ax = s_pool;
    if (t < 200) {
        float4 r;
        r.x = acc0.x * 0.2f; r.y = acc0.y * 0.2f; r.z = acc0.z * 0.2f; r.w = acc0.w * 0.2f;
        *(float4*)&s_ax[(rg * 2 + 0) * 108 + c] = r;
        r.x = acc1.x * 0.2f; r.y = acc1.y * 0.2f; r.z = acc1.z * 0.2f; r.w = acc1.w * 0.2f;
        *(float4*)&s_ax[(rg * 2 + 1) * 108 + c] = r;
    }
    const float4* ww4 = (const float4*)W_w;
    gl2lds16(ww4 + t, &s_w[0][t * 4]);
    if (t < 244) gl2lds16(ww4 + t + 256, &s_w[0][(t + 256) * 4]);
    __syncthreads();

    // --- GEMM2: go1 = relu(Ax @ W_w + W_b), 5 tiles
    float4 o0 = make_float4(0.f, 0.f, 0.f, 0.f);
    float4 o1 = make_float4(0.f, 0.f, 0.f, 0.f);
    for (int wt = 0; wt < 5; ++wt) {
        if (wt < 4) {
            const float4* src = ww4 + (size_t)(wt + 1) * 500;
            float* wd = s_w[(wt + 1) & 1];
            gl2lds16(src + t, wd + t * 4);
            if (t < 244) gl2lds16(src + t + 256, wd + (t + 256) * 4);
        }
        if (t < 200) {
            const float* wb = s_w[wt & 1];
            const int kb = wt * 20;
#pragma unroll 2
            for (int kk = 0; kk < 20; kk += 4) {
                float4 a0 = *(const float4*)&s_ax[(rg * 2 + 0) * 108 + kb + kk];
                float4 a1 = *(const float4*)&s_ax[(rg * 2 + 1) * 108 + kb + kk];
                float4 v0 = *(const float4*)&wb[(kk + 0) * 100 + c];
                float4 v1 = *(const float4*)&wb[(kk + 1) * 100 + c];
                float4 v2 = *(const float4*)&wb[(kk + 2) * 100 + c];
                float4 v3 = *(const float4*)&wb[(kk + 3) * 100 + c];
                fma4(o0, a0.x, v0); fma4(o0, a0.y, v1); fma4(o0, a0.z, v2); fma4(o0, a0.w, v3);
                fma4(o1, a1.x, v0); fma4(o1, a1.y, v1); fma4(o1, a1.z, v2); fma4(o1, a1.w, v3);
            }
        }
        __syncthreads();
    }

    float* s_go = s_pool + 1728;
    if (t < 200) {
        float4 bias = *(const float4*)&W_b[c];
        o0.x = fmaxf(o0.x + bias.x, 0.f); o0.y = fmaxf(o0.y + bias.y, 0.f);
        o0.z = fmaxf(o0.z + bias.z, 0.f); o0.w = fmaxf(o0.w + bias.w, 0.f);
        o1.x = fmaxf(o1.x + bias.x, 0.f); o1.y = fmaxf(o1.y + bias.y, 0.f);
        o1.z = fmaxf(o1.z + bias.z, 0.f); o1.w = fmaxf(o1.w + bias.w, 0.f);
        *(float4*)&go1[(size_t)(b * CL + i0 + rg * 2 + 0) * CATT + c] = o0;
        *(float4*)&go1[(size_t)(b * CL + i0 + rg * 2 + 1) * CATT + c] = o1;
        *(float4*)&s_go[(rg * 2 + 0) * 104 + c] = o0;
        *(float4*)&s_go[(rg * 2 + 1) * 104 + c] = o1;
    }
    __syncthreads();

    if (t < 128) {
        int r = t >> 3, seg = t & 7;
        int e0 = seg * 13, e1 = e0 + 13 < 100 ? e0 + 13 : 100;
        float a = 0.f, c2 = 0.f;
        for (int e = e0; e < e1; ++e) {
            float v = s_go[r * 104 + e];
            a = fmaf(v, s_w1[e], a);
            c2 = fmaf(v, s_w2[e], c2);
        }
        a += __shfl_xor(a, 1); a += __shfl_xor(a, 2); a += __shfl_xor(a, 4);
        c2 += __shfl_xor(c2, 1); c2 += __shfl_xor(c2, 2); c2 += __shfl_xor(c2, 4);
        if (seg == 0) {
            s_g1row[r] = a;
            gW2S[b * CL + i0 + r] = c2;
        }
    }
    __syncthreads();

    if (t < 100) {
        float a = 0.f, s2 = 0.f;
#pragma unroll
        for (int r = 0; r < 16; ++r) {
            float v = s_go[r * 104 + t];
            a = fmaf(s_g1row[r], v, a);
            s2 += v;
        }
        atomicAdd(&t1[b * CATT + t], a);
        atomicAdd(&t2[b * CATT + t], s2);
    }
}

// ---------------------------------------------------------------------------
// k7: GCN1 with rank-1 corrections; pooled epilogue -> out1_raw atomics.
// Round-6 verified form + XCD remap of (b, ic).
// ---------------------------------------------------------------------------
__global__ __launch_bounds__(256, 3) void k7_gcn1(
    const float* __restrict__ adjW, const float* __restrict__ go1,
    const float* __restrict__ W_w, const float* __restrict__ W_b,
    const float* __restrict__ t1, const float* __restrict__ t2,
    const float* __restrict__ gW2S, const float* __restrict__ Wx_b,
    const float* __restrict__ amask, float* __restrict__ out1_raw)
{
    __shared__ float s_pool[16 * 260];
    __shared__ float s_w[2][3200];
    int b, ic;
    xcd_map(blockIdx.x, b, ic);
    const int i0 = ic * 16;
    const int t = threadIdx.x;

    {
        const float4* asrc = (const float4*)adjW + (size_t)(b * CL + i0) * 64;
#pragma unroll
        for (int m = 0; m < 4; ++m) {
            int i = t + 256 * m;
            gl2lds16(asrc + i, &s_pool[(i >> 6) * 260 + (i & 63) * 4]);
        }
    }
    const int cg = t % 25, rg = t / 25;
    const int c = cg * 4;
    const float4* g4 = (const float4*)go1 + (size_t)b * 6400;
    gl2lds16(g4 + t,       &s_w[0][(t      ) * 4]);
    gl2lds16(g4 + t + 256, &s_w[0][(t + 256) * 4]);
    gl2lds16(g4 + t + 512, &s_w[0][(t + 512) * 4]);
    if (t < 32) gl2lds16(g4 + t + 768, &s_w[0][(t + 768) * 4]);
    __syncthreads();

    float4 acc0 = make_float4(0.f, 0.f, 0.f, 0.f);
    float4 acc1 = make_float4(0.f, 0.f, 0.f, 0.f);
    for (int jt = 0; jt < 8; ++jt) {
        if (jt < 7) {
            const float4* src = g4 + (size_t)(jt + 1) * 800;
            float* wd = s_w[(jt + 1) & 1];
            gl2lds16(src + t,       wd + (t      ) * 4);
            gl2lds16(src + t + 256, wd + (t + 256) * 4);
            gl2lds16(src + t + 512, wd + (t + 512) * 4);
            if (t < 32) gl2lds16(src + t + 768, wd + (t + 768) * 4);
        }
        if (t < 200) {
            const float* wb = s_w[jt & 1];
#pragma unroll 2
            for (int kk = 0; kk < 32; kk += 4) {
                float4 a0 = *(const float4*)&s_pool[(rg * 2 + 0) * 260 + jt * 32 + kk];
                float4 a1 = *(const float4*)&s_pool[(rg * 2 + 1) * 260 + jt * 32 + kk];
                float4 v0 = *(const float4*)&wb[(kk + 0) * 100 + c];
                float4 v1 = *(const float4*)&wb[(kk + 1) * 100 + c];
                float4 v2 = *(const float4*)&wb[(kk + 2) * 100 + c];
                float4 v3 = *(const float4*)&wb[(kk + 3) * 100 + c];
                fma4(acc0, a0.x, v0); fma4(acc0, a0.y, v1); fma4(acc0, a0.z, v2); fma4(acc0, a0.w, v3);
                fma4(acc1, a1.x, v0); fma4(acc1, a1.y, v1); fma4(acc1, a1.z, v2); fma4(acc1, a1.w, v3);
            }
        }
        __syncthreads();
    }

    float* s_ax = s_pool;
    if (t < 200) {
        float wxbs = Wx_b[0] + Wx_b[1] + Wx_b[2] + Wx_b[3] + Wx_b[4];
        float4 t1v = *(const float4*)&t1[b * CATT + c];
        float4 t2v = *(const float4*)&t2[b * CATT + c];
        float gw0 = gW2S[b * CL + i0 + rg * 2 + 0] + wxbs;
        float gw1 = gW2S[b * CL + i0 + rg * 2 + 1] + wxbs;
        float4 r;
        r.x = (acc0.x + t1v.x + gw0 * t2v.x) * 0.2f;
        r.y = (acc0.y + t1v.y + gw0 * t2v.y) * 0.2f;
        r.z = (acc0.z + t1v.z + gw0 * t2v.z) * 0.2f;
        r.w = (acc0.w + t1v.w + gw0 * t2v.w) * 0.2f;
        *(float4*)&s_ax[(rg * 2 + 0) * 108 + c] = r;
        r.x = (acc1.x + t1v.x + gw1 * t2v.x) * 0.2f;
        r.y = (acc1.y + t1v.y + gw1 * t2v.y) * 0.2f;
        r.z = (acc1.z + t1v.z + gw1 * t2v.z) * 0.2f;
        r.w = (acc1.w + t1v.w + gw1 * t2v.w) * 0.2f;
        *(float4*)&s_ax[(rg * 2 + 1) * 108 + c] = r;
    }
    const float4* ww4 = (const float4*)W_w;
    gl2lds16(ww4 + t, &s_w[0][t * 4]);
    if (t < 244) gl2lds16(ww4 + t + 256, &s_w[0][(t + 256) * 4]);
    __syncthreads();

    float4 o0 = make_float4(0.f, 0.f, 0.f, 0.f);
    float4 o1 = make_float4(0.f, 0.f, 0.f, 0.f);
    for (int wt = 0; wt < 5; ++wt) {
        if (wt < 4) {
            const float4* src = ww4 + (size_t)(wt + 1) * 500;
            float* wd = s_w[(wt + 1) & 1];
            gl2lds16(src + t, wd + t * 4);
            if (t < 244) gl2lds16(src + t + 256, wd + (t + 256) * 4);
        }
        if (t < 200) {
            const float* wb = s_w[wt & 1];
            const int kb = wt * 20;
#pragma unroll 2
            for (int kk = 0; kk < 20; kk += 4) {
                float4 a0 = *(const float4*)&s_ax[(rg * 2 + 0) * 108 + kb + kk];
                float4 a1 = *(const float4*)&s_ax[(rg * 2 + 1) * 108 + kb + kk];
                float4 v0 = *(const float4*)&wb[(kk + 0) * 100 + c];
                float4 v1 = *(const float4*)&wb[(kk + 1) * 100 + c];
                float4 v2 = *(const float4*)&wb[(kk + 2) * 100 + c];
                float4 v3 = *(const float4*)&wb[(kk + 3) * 100 + c];
                fma4(o0, a0.x, v0); fma4(o0, a0.y, v1); fma4(o0, a0.z, v2); fma4(o0, a0.w, v3);
                fma4(o1, a1.x, v0); fma4(o1, a1.y, v1); fma4(o1, a1.z, v2); fma4(o1, a1.w, v3);
            }
        }
        __syncthreads();
    }

    if (t < 200) {
        float4 bias = *(const float4*)&W_b[c];
        o0.x = fmaxf(o0.x + bias.x, 0.f); o0.y = fmaxf(o0.y + bias.y, 0.f);
        o0.z = fmaxf(o0.z + bias.z, 0.f); o0.w = fmaxf(o0.w + bias.w, 0.f);
        o1.x = fmaxf(o1.x + bias.x, 0.f); o1.y = fmaxf(o1.y + bias.y, 0.f);
        o1.z = fmaxf(o1.z + bias.z, 0.f); o1.w = fmaxf(o1.w + bias.w, 0.f);
        float4 ov[2] = { o0, o1 };
#pragma unroll
        for (int q = 0; q < 2; ++q) {
            int row = b * CL + i0 + rg * 2 + q;
            float m = amask[row];
            if (m != 0.f) {
                atomicAdd(&out1_raw[b * CATT + c + 0], m * ov[q].x);
                atomicAdd(&out1_raw[b * CATT + c + 1], m * ov[q].y);
                atomicAdd(&out1_raw[b * CATT + c + 2], m * ov[q].z);
                atomicAdd(&out1_raw[b * CATT + c + 3], m * ov[q].w);
            }
        }
    }
}

// ---------------------------------------------------------------------------
__global__ __launch_bounds__(64) void k8_small(
    const float* __restrict__ out1_raw, const float* __restrict__ amask,
    const float* __restrict__ clf_w, const float* __restrict__ clf_b,
    float* __restrict__ out)
{
    const int b = blockIdx.x, t = threadIdx.x;
    float4 mv = ((const float4*)amask)[b * 64 + t];
    float wn = mv.x + mv.y + mv.z + mv.w;
#pragma unroll
    for (int o = 32; o; o >>= 1) wn += __shfl_xor(wn, o);
    if (t < 3) {
        float rwn = 1.f / wn;
        float a = clf_b[t];
        for (int d = 0; d < CATT; ++d)
            a = fmaf(out1_raw[b * CATT + d] * rwn, clf_w[d * 3 + t], a);
        out[b * 3 + t] = a;
    }
}

// ---------------------------------------------------------------------------
extern "C" void kernel_launch(void* const* d_in, const int* in_sizes, int n_in,
                              void* d_out, int out_size, void* d_ws, size_t ws_size,
                              hipStream_t stream) {
    const float* seq     = (const float*)d_in[0];
    const int*   srcm    = (const int*)d_in[1];
    const float* amask   = (const float*)d_in[2];
    const float* shortm  = (const float*)d_in[3];
    const float* ln_a    = (const float*)d_in[4];
    const float* ln_b    = (const float*)d_in[5];
    const float* Wxx_w   = (const float*)d_in[6];
    const float* Wxx_b   = (const float*)d_in[7];
    const float* q_w     = (const float*)d_in[8];
    const float* q_b     = (const float*)d_in[9];
    const float* k_w     = (const float*)d_in[10];
    const float* k_b     = (const float*)d_in[11];
    const float* dense_w = (const float*)d_in[12];
    const float* dense_b = (const float*)d_in[13];
    const float* bias_m  = (const float*)d_in[14];
    const float* W_w     = (const float*)d_in[15];
    const float* W_b     = (const float*)d_in[16];
    const float* Wx_w    = (const float*)d_in[17];
    const float* Wx_b    = (const float*)d_in[18];
    const float* clf_w   = (const float*)d_in[19];
    const float* clf_b   = (const float*)d_in[20];
    float* out = (float*)d_out;

    float* ws         = (float*)d_ws;
    float* g          = ws;
    float* qt         = g + 819200;
    float* ktb        = qt + 819200;
    float* go1        = ktb + 819200;
    float* adjW       = go1 + 819200;
    float* aspect_raw = adjW + 2097152;
    float* t1         = aspect_raw + 3200;
    float* t2         = t1 + 3200;
    float* out1_raw   = t2 + 3200;
    float* gW2S       = out1_raw + 3200;

    hipMemsetAsync(aspect_raw, 0, 4 * 3200 * sizeof(float), stream);
    hipLaunchKernelGGL(k1_fused, dim3(512), dim3(256), 0, stream, seq, ln_a, ln_b,
                       Wxx_w, Wxx_b, q_w, q_b, k_w, k_b, amask, g, qt, ktb, aspect_raw);
    hipLaunchKernelGGL(k45_attn_gcn0, dim3(512), dim3(256), 0, stream,
                       qt, ktb, aspect_raw, amask, dense_w, dense_b, bias_m, srcm,
                       shortm, Wx_w, g, W_w, W_b, adjW, go1, t1, t2, gW2S);
    hipLaunchKernelGGL(k7_gcn1, dim3(512), dim3(256), 0, stream,
                       adjW, go1, W_w, W_b, t1, t2, gW2S, Wx_b, amask, out1_raw);
    hipLaunchKernelGGL(k8_small, dim3(32), dim3(64), 0, stream,
                       out1_raw, amask, clf_w, clf_b, out);
}